// Round 2
// baseline (512.610 us; speedup 1.0000x reference)
//
#include <hip/hip_runtime.h>
#include <hip/hip_bf16.h>

using u16 = unsigned short;
typedef __attribute__((ext_vector_type(8))) short bf16x8;
typedef __attribute__((ext_vector_type(4))) float f32x4;
typedef __attribute__((ext_vector_type(8))) u16 u16x8;
typedef __attribute__((ext_vector_type(4))) u16 u16x4;

#define B_ 2
#define N_ 4096
#define E_ 1024
#define R_ 128
#define H_ 8
#define M_ 8192      // B*N
#define CHUNK_ 128
#define NC_ 32       // N/CHUNK
#define BH_ 16       // B*H

__device__ __forceinline__ float b2f(u16 u) { return __uint_as_float(((unsigned)u) << 16); }
__device__ __forceinline__ u16 f2b(float f) {
  unsigned u = __float_as_uint(f);
  return (u16)((u + 0x7fffu + ((u >> 16) & 1u)) >> 16);   // RNE
}
__device__ __forceinline__ float sigm(float x) { return 1.0f / (1.0f + expf(-x)); }

// ---------------------------------------------------------------------------
// fp32 -> bf16 conversion of x + 9 weight tensors (inputs are fp32 per the
// reference; MFMA needs bf16). One float4 per thread, flat id -> segment.
// ---------------------------------------------------------------------------
struct CvtArgs {
  const float* src[10];
  u16* dst[10];
};

__global__ void __launch_bounds__(256) cvt_all(CvtArgs a) {
  int idx = blockIdx.x * 256 + threadIdx.x;   // float4 index, grid sized exactly
  const int sz4[10] = {2097152, 262144, 262144, 262144, 2048,
                       32768, 32768, 32768, 32768, 262144};
  int off = idx, seg = 0;
#pragma unroll
  for (int i = 0; i < 9; i++) {
    if (seg == i && off >= sz4[i]) { off -= sz4[i]; seg = i + 1; }
  }
  float4 v = ((const float4*)a.src[seg])[off];
  u16x4 r;
  r[0] = f2b(v.x); r[1] = f2b(v.y); r[2] = f2b(v.z); r[3] = f2b(v.w);
  ((u16x4*)a.dst[seg])[off] = r;
}

// ---------------------------------------------------------------------------
// GEMM: C[M,N] = act( X[M,K] @ W[N,K]^T ), bf16 inputs, fp32 accum.
// 128x128 block tile, BK=32, 4 waves, each wave a 64x64 region of 16x16 MFMA
// tiles. global_load_lds width-16 staging (m97 pattern). ACT: 0 none, 1 silu,
// 2 sigmoid. OutT: float or u16(bf16).
// ---------------------------------------------------------------------------
template<int ACT, typename OutT>
__global__ void __launch_bounds__(256) gemm_bt(const u16* __restrict__ X, const u16* __restrict__ W,
                                               OutT* __restrict__ C, int M, int N, int K) {
  __shared__ u16 As[128 * 32];
  __shared__ u16 Bs[128 * 32];
  const int m0 = blockIdx.x * 128;
  const int n0 = blockIdx.y * 128;
  const int tid = threadIdx.x;
  const int wave = tid >> 6;
  const int lane = tid & 63;
  const int wr = wave >> 1, wc = wave & 1;

  const u16* Ap = X + (size_t)(m0 + wave * 32 + (lane >> 2)) * K + (lane & 3) * 8;
  const u16* Bp = W + (size_t)(n0 + wave * 32 + (lane >> 2)) * K + (lane & 3) * 8;
  u16* AsW = As + wave * 32 * 32;
  u16* BsW = Bs + wave * 32 * 32;

  f32x4 acc[4][4];
#pragma unroll
  for (int i = 0; i < 4; i++)
#pragma unroll
    for (int j = 0; j < 4; j++) acc[i][j] = (f32x4){0.f, 0.f, 0.f, 0.f};

  for (int k0 = 0; k0 < K; k0 += 32) {
    __builtin_amdgcn_global_load_lds((const __attribute__((address_space(1))) unsigned int*)(Ap + k0),
                                     (__attribute__((address_space(3))) unsigned int*)(AsW), 16, 0, 0);
    __builtin_amdgcn_global_load_lds((const __attribute__((address_space(1))) unsigned int*)(Ap + 16 * (size_t)K + k0),
                                     (__attribute__((address_space(3))) unsigned int*)(AsW + 16 * 32), 16, 0, 0);
    __builtin_amdgcn_global_load_lds((const __attribute__((address_space(1))) unsigned int*)(Bp + k0),
                                     (__attribute__((address_space(3))) unsigned int*)(BsW), 16, 0, 0);
    __builtin_amdgcn_global_load_lds((const __attribute__((address_space(1))) unsigned int*)(Bp + 16 * (size_t)K + k0),
                                     (__attribute__((address_space(3))) unsigned int*)(BsW + 16 * 32), 16, 0, 0);
    __syncthreads();   // compiler drains vmcnt before barrier -> staging visible
    bf16x8 af[4], bfr[4];
#pragma unroll
    for (int mi = 0; mi < 4; mi++)
      af[mi] = *(const bf16x8*)&As[(wr * 64 + mi * 16 + (lane & 15)) * 32 + (lane >> 4) * 8];
#pragma unroll
    for (int ni = 0; ni < 4; ni++)
      bfr[ni] = *(const bf16x8*)&Bs[(wc * 64 + ni * 16 + (lane & 15)) * 32 + (lane >> 4) * 8];
#pragma unroll
    for (int mi = 0; mi < 4; mi++)
#pragma unroll
      for (int ni = 0; ni < 4; ni++)
        acc[mi][ni] = __builtin_amdgcn_mfma_f32_16x16x32_bf16(af[mi], bfr[ni], acc[mi][ni], 0, 0, 0);
    __syncthreads();   // protect LDS from next iteration's staging
  }
  // epilogue: C/D layout col=lane&15, row=(lane>>4)*4+r
#pragma unroll
  for (int mi = 0; mi < 4; mi++) {
#pragma unroll
    for (int ni = 0; ni < 4; ni++) {
      int col = n0 + wc * 64 + ni * 16 + (lane & 15);
      int rbase = m0 + wr * 64 + mi * 16 + (lane >> 4) * 4;
#pragma unroll
      for (int r = 0; r < 4; r++) {
        float v = acc[mi][ni][r];
        if (ACT == 1) v = v * sigm(v);
        else if (ACT == 2) v = sigm(v);
        size_t idx = (size_t)(rbase + r) * N + col;
        if constexpr (sizeof(OutT) == 2) C[idx] = f2b(v);
        else C[idx] = v;
      }
    }
  }
}

// ---------------------------------------------------------------------------
// f = x @ Wf^T  ->  log_f[b,h,n] = log(lb_h + (1-lb_h)*sigmoid(f))
// one wave per row; lane holds 16 x-values. x/Wf bf16 copies; llb fp32.
// ---------------------------------------------------------------------------
__global__ void __launch_bounds__(256) logf_proj(const u16* __restrict__ x, const u16* __restrict__ Wf,
                                                 const float* __restrict__ llb, float* __restrict__ LOGF) {
  int row = blockIdx.x * 4 + (threadIdx.x >> 6);
  int lane = threadIdx.x & 63;
  const u16* xr = x + (size_t)row * E_ + lane * 16;
  u16x8 xa = *(const u16x8*)xr;
  u16x8 xb = *(const u16x8*)(xr + 8);
  float xv[16];
#pragma unroll
  for (int i = 0; i < 8; i++) { xv[i] = b2f(xa[i]); xv[8 + i] = b2f(xb[i]); }
  int b = row >> 12, n = row & (N_ - 1);
#pragma unroll
  for (int h = 0; h < H_; h++) {
    const u16* wr = Wf + (size_t)h * E_ + lane * 16;
    u16x8 wa = *(const u16x8*)wr;
    u16x8 wb = *(const u16x8*)(wr + 8);
    float s = 0.f;
#pragma unroll
    for (int i = 0; i < 8; i++) s += xv[i] * b2f(wa[i]) + xv[8 + i] * b2f(wb[i]);
#pragma unroll
    for (int m = 1; m < 64; m <<= 1) s += __shfl_xor(s, m);
    if (lane == h) {
      float lb = expf(llb[h]);
      float fg = lb + (1.f - lb) * sigm(s);
      LOGF[(size_t)(b * H_ + h) * N_ + n] = logf(fg);
    }
  }
}

// ---------------------------------------------------------------------------
// Householder: q = (q - 2*(q.beta)/(|beta|^2+1e-12)*beta) * R^-0.5  (in place)
// ---------------------------------------------------------------------------
__global__ void __launch_bounds__(256) householder(float* __restrict__ Q, const float* __restrict__ BETA) {
  int row = blockIdx.x;
  int tid = threadIdx.x;
  float* q = Q + (size_t)row * E_;
  const float* bt = BETA + (size_t)row * E_;
  float4 q4 = *(const float4*)(q + tid * 4);
  float4 b4 = *(const float4*)(bt + tid * 4);
  float ss = b4.x * b4.x + b4.y * b4.y + b4.z * b4.z + b4.w * b4.w;
  float qd = q4.x * b4.x + q4.y * b4.y + q4.z * b4.z + q4.w * b4.w;
  __shared__ float red[8];
#pragma unroll
  for (int m = 1; m < 64; m <<= 1) { ss += __shfl_xor(ss, m); qd += __shfl_xor(qd, m); }
  int wid = tid >> 6;
  if ((tid & 63) == 0) { red[wid] = ss; red[4 + wid] = qd; }
  __syncthreads();
  ss = red[0] + red[1] + red[2] + red[3];
  qd = red[4] + red[5] + red[6] + red[7];
  float coef = 2.f * qd / (ss + 1e-12f);
  const float scale = 0.08838834764831845f;  // 128^-0.5 folded into q here
  q4.x = (q4.x - coef * b4.x) * scale;
  q4.y = (q4.y - coef * b4.y) * scale;
  q4.z = (q4.z - coef * b4.z) * scale;
  q4.w = (q4.w - coef * b4.w) * scale;
  *(float4*)(q + tid * 4) = q4;
}

// inclusive scan of the 128 log-decay values of one chunk into cum[] (wave 0)
__device__ __forceinline__ void scan_chunk(const float* __restrict__ lf, float* cum, int tid) {
  if (tid < 64) {
    float a = lf[tid], b = lf[tid + 64];
#pragma unroll
    for (int off = 1; off < 64; off <<= 1) {
      float t = __shfl_up(a, off);  if (tid >= off) a += t;
      float t2 = __shfl_up(b, off); if (tid >= off) b += t2;
    }
    b += __shfl(a, 63);
    cum[tid] = a; cum[tid + 64] = b;
  }
  __syncthreads();
}

// ---------------------------------------------------------------------------
// Phase A: per (bh, chunk): U[k][v] = sum_j exp(cumC-cum_j) * K[j][k] * V[j][v]
// DC = exp(cumC). 16x16 threads, 8x8 register tiles, 16-row j slabs in LDS.
// ---------------------------------------------------------------------------
__global__ void __launch_bounds__(256) gla_phaseA(const float* __restrict__ Kb, const float* __restrict__ Vb,
                                                  const float* __restrict__ LOGF,
                                                  float* __restrict__ U, float* __restrict__ DC) {
  const int blk = blockIdx.x;
  const int bh = blk >> 5, c = blk & 31;
  const int b = bh >> 3, h = bh & 7;
  const int tid = threadIdx.x;
  __shared__ float cum[CHUNK_];
  __shared__ float Ks[16][132];
  __shared__ float Vs[16][132];
  scan_chunk(LOGF + (size_t)bh * N_ + c * CHUNK_, cum, tid);
  const float cumC = cum[127];
  float acc[8][8];
#pragma unroll
  for (int i = 0; i < 8; i++)
#pragma unroll
    for (int j = 0; j < 8; j++) acc[i][j] = 0.f;
  const int tk = tid >> 4, tv = tid & 15;
  const size_t rowbase = ((size_t)b * N_ + (size_t)c * CHUNK_) * E_ + (size_t)h * R_;
  const int sj = tid >> 4;
  const int sc = (tid & 15) * 8;
  for (int j0 = 0; j0 < CHUNK_; j0 += 16) {
    __syncthreads();
    {
      int j = j0 + sj;
      float w = expf(cumC - cum[j]);
      const float* kp = Kb + rowbase + (size_t)j * E_ + sc;
      const float* vp = Vb + rowbase + (size_t)j * E_ + sc;
      float4 k1 = *(const float4*)kp, k2 = *(const float4*)(kp + 4);
      float4 v1 = *(const float4*)vp, v2 = *(const float4*)(vp + 4);
      float4 kw1 = {k1.x * w, k1.y * w, k1.z * w, k1.w * w};
      float4 kw2 = {k2.x * w, k2.y * w, k2.z * w, k2.w * w};
      *(float4*)&Ks[sj][sc] = kw1; *(float4*)&Ks[sj][sc + 4] = kw2;
      *(float4*)&Vs[sj][sc] = v1;  *(float4*)&Vs[sj][sc + 4] = v2;
    }
    __syncthreads();
#pragma unroll
    for (int jj = 0; jj < 16; jj++) {
      float4 a1 = *(const float4*)&Ks[jj][tk * 8];
      float4 a2 = *(const float4*)&Ks[jj][tk * 8 + 4];
      float4 b1 = *(const float4*)&Vs[jj][tv * 8];
      float4 b2 = *(const float4*)&Vs[jj][tv * 8 + 4];
      float av[8] = {a1.x, a1.y, a1.z, a1.w, a2.x, a2.y, a2.z, a2.w};
      float bv[8] = {b1.x, b1.y, b1.z, b1.w, b2.x, b2.y, b2.z, b2.w};
#pragma unroll
      for (int i = 0; i < 8; i++)
#pragma unroll
        for (int j = 0; j < 8; j++) acc[i][j] += av[i] * bv[j];
    }
  }
  float* Up = U + (size_t)blk * (R_ * R_);
#pragma unroll
  for (int i = 0; i < 8; i++) {
    float4 o1 = {acc[i][0], acc[i][1], acc[i][2], acc[i][3]};
    float4 o2 = {acc[i][4], acc[i][5], acc[i][6], acc[i][7]};
    *(float4*)(Up + (size_t)(tk * 8 + i) * R_ + tv * 8) = o1;
    *(float4*)(Up + (size_t)(tk * 8 + i) * R_ + tv * 8 + 4) = o2;
  }
  if (tid == 0) DC[blk] = expf(cumC);
}

// ---------------------------------------------------------------------------
// Phase B: propagate chunk-start states. elementwise-parallel over (bh, k, v).
// ---------------------------------------------------------------------------
__global__ void __launch_bounds__(256) gla_phaseB(const float* __restrict__ U, const float* __restrict__ DC,
                                                  float* __restrict__ SS) {
  int idx = blockIdx.x * 256 + threadIdx.x;
  int bh = idx >> 14;
  int e = idx & 16383;
  float s = 0.f;
  for (int c = 0; c < NC_; c++) {
    size_t off = ((size_t)bh * NC_ + c) * 16384 + e;
    SS[off] = s;
    s = DC[bh * NC_ + c] * s + U[off];
  }
}

__device__ __forceinline__ void fma4x8(float (*acc)[8], float4 a4, float4 b1, float4 b2) {
  float av[4] = {a4.x, a4.y, a4.z, a4.w};
  float bv[8] = {b1.x, b1.y, b1.z, b1.w, b2.x, b2.y, b2.z, b2.w};
#pragma unroll
  for (int ii = 0; ii < 4; ii++)
#pragma unroll
    for (int jj = 0; jj < 8; jj++) acc[ii][jj] += av[ii] * bv[jj];
}

// ---------------------------------------------------------------------------
// Phase C: per (bh, chunk): o_i = exp(cum_i)*q_i@Sstart
//                               + sum_{j<=i} exp(cum_i-cum_j)(q_i.k_j) v_j
// i processed in two halves of 64 to keep LDS at 56 KB (2 blocks/CU).
// A-operand slabs stored transposed [contraction][i] for aligned float4 reads.
// ---------------------------------------------------------------------------
__global__ void __launch_bounds__(256) gla_phaseC(const float* __restrict__ Qb, const float* __restrict__ Kb,
                                                  const float* __restrict__ Vb, const float* __restrict__ LOGF,
                                                  const float* __restrict__ SS, float* __restrict__ Ob) {
  const int blk = blockIdx.x;
  const int bh = blk >> 5, c = blk & 31;
  const int b = bh >> 3, h = bh & 7;
  const int tid = threadIdx.x;
  __shared__ float cum[CHUNK_];
  __shared__ float SscT[128][68];   // scores transposed [j][i_local]
  __shared__ float SaT[16][64];     // A-slab transposed [r][i_local]
  __shared__ float SkT[16][132];    // K-slab transposed [r][j]
  __shared__ float Sb[16][132];     // B-slab [contraction][v]
  scan_chunk(LOGF + (size_t)bh * N_ + c * CHUNK_, cum, tid);
  const size_t rowbase = ((size_t)b * N_ + (size_t)c * CHUNK_) * E_ + (size_t)h * R_;
  const float* Sst = SS + (size_t)blk * (R_ * R_);
  const int ti = tid >> 4, tj = tid & 15;
  float acc[4][8];
  for (int ih = 0; ih < 2; ih++) {
    const int i0 = ih * 64;
    // ---- scores = Q K^T ----
#pragma unroll
    for (int ii = 0; ii < 4; ii++)
#pragma unroll
      for (int jj = 0; jj < 8; jj++) acc[ii][jj] = 0.f;
    for (int r0 = 0; r0 < R_; r0 += 16) {
      __syncthreads();
      {
        int i = tid >> 2, rr = (tid & 3) * 4;
        float4 q4 = *(const float4*)(Qb + rowbase + (size_t)(i0 + i) * E_ + r0 + rr);
        SaT[rr + 0][i] = q4.x; SaT[rr + 1][i] = q4.y; SaT[rr + 2][i] = q4.z; SaT[rr + 3][i] = q4.w;
      }
      {
        int j = tid >> 1, rr = (tid & 1) * 8;
        const float* kp = Kb + rowbase + (size_t)j * E_ + r0 + rr;
        float4 k1 = *(const float4*)kp, k2 = *(const float4*)(kp + 4);
        SkT[rr + 0][j] = k1.x; SkT[rr + 1][j] = k1.y; SkT[rr + 2][j] = k1.z; SkT[rr + 3][j] = k1.w;
        SkT[rr + 4][j] = k2.x; SkT[rr + 5][j] = k2.y; SkT[rr + 6][j] = k2.z; SkT[rr + 7][j] = k2.w;
      }
      __syncthreads();
#pragma unroll
      for (int t = 0; t < 16; t++)
        fma4x8(acc, *(const float4*)&SaT[t][ti * 4],
               *(const float4*)&SkT[t][tj * 8], *(const float4*)&SkT[t][tj * 8 + 4]);
    }
    __syncthreads();
    // ---- mask + decay-weight, stash in LDS ----
#pragma unroll
    for (int ii = 0; ii < 4; ii++) {
      int il = ti * 4 + ii, i = i0 + il;
      float ci = cum[i];
#pragma unroll
      for (int jj = 0; jj < 8; jj++) {
        int j = tj * 8 + jj;
        float w = (j <= i) ? expf(ci - cum[j]) : 0.f;
        SscT[j][il] = acc[ii][jj] * w;
      }
    }
    // ---- term1: Q @ Sstart ----
#pragma unroll
    for (int ii = 0; ii < 4; ii++)
#pragma unroll
      for (int jj = 0; jj < 8; jj++) acc[ii][jj] = 0.f;
    for (int k0 = 0; k0 < R_; k0 += 16) {
      __syncthreads();
      {
        int i = tid >> 2, rr = (tid & 3) * 4;
        float4 q4 = *(const float4*)(Qb + rowbase + (size_t)(i0 + i) * E_ + k0 + rr);
        SaT[rr + 0][i] = q4.x; SaT[rr + 1][i] = q4.y; SaT[rr + 2][i] = q4.z; SaT[rr + 3][i] = q4.w;
      }
      {
        int kk = tid >> 4, vv = (tid & 15) * 8;
        const float* sp = Sst + (size_t)(k0 + kk) * R_ + vv;
        float4 s1 = *(const float4*)sp, s2 = *(const float4*)(sp + 4);
        *(float4*)&Sb[kk][vv] = s1; *(float4*)&Sb[kk][vv + 4] = s2;
      }
      __syncthreads();
#pragma unroll
      for (int t = 0; t < 16; t++)
        fma4x8(acc, *(const float4*)&SaT[t][ti * 4],
               *(const float4*)&Sb[t][tj * 8], *(const float4*)&Sb[t][tj * 8 + 4]);
    }
#pragma unroll
    for (int ii = 0; ii < 4; ii++) {
      float ei = expf(cum[i0 + ti * 4 + ii]);
#pragma unroll
      for (int jj = 0; jj < 8; jj++) acc[ii][jj] *= ei;
    }
    // ---- term2: P @ V (only slabs with j <= i_max) ----
    const int j0max = i0 + 64;
    for (int j0 = 0; j0 < j0max; j0 += 16) {
      __syncthreads();
      {
        int kk = tid >> 4, vv = (tid & 15) * 8;
        const float* vp = Vb + rowbase + (size_t)(j0 + kk) * E_ + vv;
        float4 v1 = *(const float4*)vp, v2 = *(const float4*)(vp + 4);
        *(float4*)&Sb[kk][vv] = v1; *(float4*)&Sb[kk][vv + 4] = v2;
      }
      __syncthreads();
#pragma unroll
      for (int t = 0; t < 16; t++)
        fma4x8(acc, *(const float4*)&SscT[j0 + t][ti * 4],
               *(const float4*)&Sb[t][tj * 8], *(const float4*)&Sb[t][tj * 8 + 4]);
    }
    // ---- write O ----
#pragma unroll
    for (int ii = 0; ii < 4; ii++) {
      int i = i0 + ti * 4 + ii;
      float4 o1 = {acc[ii][0], acc[ii][1], acc[ii][2], acc[ii][3]};
      float4 o2 = {acc[ii][4], acc[ii][5], acc[ii][6], acc[ii][7]};
      float* op = Ob + rowbase + (size_t)i * E_ + tj * 8;
      *(float4*)op = o1; *(float4*)(op + 4) = o2;
    }
  }
}

// ---------------------------------------------------------------------------
// o = o * gate (bf16); LayerNorm(weight-only, fp32 gamma) -> bf16 for final GEMM
// ---------------------------------------------------------------------------
__global__ void __launch_bounds__(256) gate_ln(const float* __restrict__ O, const u16* __restrict__ G,
                                               const float* __restrict__ gamma, u16* __restrict__ OLN) {
  int row = blockIdx.x, tid = threadIdx.x;
  const float* op = O + (size_t)row * E_;
  float4 o4 = *(const float4*)(op + tid * 4);
  u16x4 g4 = *(const u16x4*)(G + (size_t)row * E_ + tid * 4);
  float x0 = o4.x * b2f(g4[0]), x1 = o4.y * b2f(g4[1]);
  float x2 = o4.z * b2f(g4[2]), x3 = o4.w * b2f(g4[3]);
  float s = x0 + x1 + x2 + x3;
  float sq = x0 * x0 + x1 * x1 + x2 * x2 + x3 * x3;
  __shared__ float red[8];
#pragma unroll
  for (int m = 1; m < 64; m <<= 1) { s += __shfl_xor(s, m); sq += __shfl_xor(sq, m); }
  int wid = tid >> 6;
  if ((tid & 63) == 0) { red[wid] = s; red[4 + wid] = sq; }
  __syncthreads();
  s = red[0] + red[1] + red[2] + red[3];
  sq = red[4] + red[5] + red[6] + red[7];
  float mu = s * (1.f / 1024.f);
  float var = sq * (1.f / 1024.f) - mu * mu;
  float rs = rsqrtf(var + 1e-5f);
  int e = tid * 4;
  u16x4 r4;
  r4[0] = f2b((x0 - mu) * rs * gamma[e + 0]);
  r4[1] = f2b((x1 - mu) * rs * gamma[e + 1]);
  r4[2] = f2b((x2 - mu) * rs * gamma[e + 2]);
  r4[3] = f2b((x3 - mu) * rs * gamma[e + 3]);
  *(u16x4*)(OLN + (size_t)row * E_ + e) = r4;
}

// ---------------------------------------------------------------------------
extern "C" void kernel_launch(void* const* d_in, const int* in_sizes, int n_in,
                              void* d_out, int out_size, void* d_ws, size_t ws_size,
                              hipStream_t stream) {
  (void)in_sizes; (void)n_in; (void)out_size; (void)ws_size;
  const float* x   = (const float*)d_in[0];
  const float* llb = (const float*)d_in[1];
  const float* Wq  = (const float*)d_in[2];
  const float* Wk  = (const float*)d_in[3];
  const float* Wv  = (const float*)d_in[4];
  const float* Wf  = (const float*)d_in[5];
  const float* Wb1 = (const float*)d_in[6];
  const float* Wb2 = (const float*)d_in[7];
  const float* Wg1 = (const float*)d_in[8];
  const float* Wg2 = (const float*)d_in[9];
  const float* gm  = (const float*)d_in[10];
  const float* Wo  = (const float*)d_in[11];
  float* out = (float*)d_out;

  char* ws = (char*)d_ws;
  const size_t SZF = (size_t)M_ * E_ * 4;            // 33.5 MB per fp32 [M,E]
  float* Q     = (float*)(ws + 0 * SZF);             // q (later OLN overlay)
  float* K     = (float*)(ws + 1 * SZF);
  float* V     = (float*)(ws + 2 * SZF);
  float* BUFA  = (float*)(ws + 3 * SZF);             // beta -> U -> O
  float* SST   = (float*)(ws + 4 * SZF);             // chunk-start states
  u16*   GATEb = (u16*)(ws + 5 * SZF);               // bf16 gate [M,E]
  u16*   XB    = (u16*)(ws + 5 * SZF + (size_t)M_ * E_ * 2);
  u16*   WQb   = XB + (size_t)M_ * E_;               // bf16 weight copies
  u16*   WKb   = WQb + (size_t)E_ * E_;
  u16*   WVb   = WKb + (size_t)E_ * E_;
  u16*   WFb   = WVb + (size_t)E_ * E_;
  u16*   WB1b  = WFb + (size_t)H_ * E_;
  u16*   WB2b  = WB1b + (size_t)R_ * E_;
  u16*   WG1b  = WB2b + (size_t)E_ * R_;
  u16*   WG2b  = WG1b + (size_t)R_ * E_;
  u16*   WOb   = WG2b + (size_t)E_ * R_;
  u16*   T1    = WOb + (size_t)E_ * E_;              // [M,R] bf16 low-rank tmp
  float* LOGF  = (float*)(T1 + (size_t)M_ * R_);
  float* DC    = LOGF + (size_t)BH_ * N_;
  u16*   OLN   = (u16*)Q;                            // overlays q (dead by then)
  // total ws usage ~213 MB

  CvtArgs ca;
  ca.src[0] = x;   ca.dst[0] = XB;
  ca.src[1] = Wq;  ca.dst[1] = WQb;
  ca.src[2] = Wk;  ca.dst[2] = WKb;
  ca.src[3] = Wv;  ca.dst[3] = WVb;
  ca.src[4] = Wf;  ca.dst[4] = WFb;
  ca.src[5] = Wb1; ca.dst[5] = WB1b;
  ca.src[6] = Wb2; ca.dst[6] = WB2b;
  ca.src[7] = Wg1; ca.dst[7] = WG1b;
  ca.src[8] = Wg2; ca.dst[8] = WG2b;
  ca.src[9] = Wo;  ca.dst[9] = WOb;

  dim3 blk(256);
  dim3 gBig(M_ / 128, E_ / 128);   // 64 x 8
  dim3 gT1(M_ / 128, 1);           // 64 x 1

  cvt_all<<<dim3(12808), blk, 0, stream>>>(ca);                               // fp32 -> bf16 copies
  gemm_bt<1, float><<<gBig, blk, 0, stream>>>(XB, WQb, Q, M_, E_, E_);        // q = silu(xWq^T)
  gemm_bt<1, float><<<gBig, blk, 0, stream>>>(XB, WKb, K, M_, E_, E_);        // k = silu(xWk^T)
  gemm_bt<0, float><<<gBig, blk, 0, stream>>>(XB, WVb, V, M_, E_, E_);        // v
  logf_proj<<<dim3(M_ / 4), blk, 0, stream>>>(XB, WFb, llb, LOGF);            // log decay
  gemm_bt<0, u16><<<gT1, blk, 0, stream>>>(XB, WB1b, T1, M_, R_, E_);         // t1b
  gemm_bt<1, float><<<gBig, blk, 0, stream>>>(T1, WB2b, BUFA, M_, E_, R_);    // beta = silu(.)
  householder<<<dim3(M_), blk, 0, stream>>>(Q, BUFA);                         // q reflect + scale
  gemm_bt<0, u16><<<gT1, blk, 0, stream>>>(XB, WG1b, T1, M_, R_, E_);         // t1g
  gemm_bt<2, u16><<<gBig, blk, 0, stream>>>(T1, WG2b, GATEb, M_, E_, R_);     // gate = sigmoid(.)
  gla_phaseA<<<dim3(BH_ * NC_), blk, 0, stream>>>(K, V, LOGF, BUFA, DC);      // U_c, D_c
  gla_phaseB<<<dim3(BH_ * 16384 / 256), blk, 0, stream>>>(BUFA, DC, SST);     // chunk states
  gla_phaseC<<<dim3(BH_ * NC_), blk, 0, stream>>>(Q, K, V, LOGF, SST, BUFA);  // o (into BUFA)
  gate_ln<<<dim3(M_), blk, 0, stream>>>(BUFA, GATEb, gm, OLN);                // gate + LN -> bf16
  gemm_bt<0, float><<<gBig, blk, 0, stream>>>(OLN, WOb, out, M_, E_, E_);     // out = oln Wo^T (fp32)
}

// Round 3
// 406.008 us; speedup vs baseline: 1.2626x; 1.2626x over previous
//
#include <hip/hip_runtime.h>
#include <hip/hip_bf16.h>

using u16 = unsigned short;
typedef __attribute__((ext_vector_type(8))) short bf16x8;
typedef __attribute__((ext_vector_type(4))) float f32x4;
typedef __attribute__((ext_vector_type(8))) u16 u16x8;
typedef __attribute__((ext_vector_type(4))) u16 u16x4;

#define B_ 2
#define N_ 4096
#define E_ 1024
#define R_ 128
#define H_ 8
#define M_ 8192      // B*N
#define CHUNK_ 128
#define NC_ 32       // N/CHUNK
#define BH_ 16       // B*H

__device__ __forceinline__ float b2f(u16 u) { return __uint_as_float(((unsigned)u) << 16); }
__device__ __forceinline__ u16 f2b(float f) {
  unsigned u = __float_as_uint(f);
  return (u16)((u + 0x7fffu + ((u >> 16) & 1u)) >> 16);   // RNE
}
__device__ __forceinline__ float sigm(float x) { return 1.0f / (1.0f + expf(-x)); }

// ---------------------------------------------------------------------------
// fp32 -> bf16 conversion of x + 9 weight tensors.
// ---------------------------------------------------------------------------
struct CvtArgs {
  const float* src[10];
  u16* dst[10];
};

__global__ void __launch_bounds__(256) cvt_all(CvtArgs a) {
  int idx = blockIdx.x * 256 + threadIdx.x;
  const int sz4[10] = {2097152, 262144, 262144, 262144, 2048,
                       32768, 32768, 32768, 32768, 262144};
  int off = idx, seg = 0;
#pragma unroll
  for (int i = 0; i < 9; i++) {
    if (seg == i && off >= sz4[i]) { off -= sz4[i]; seg = i + 1; }
  }
  float4 v = ((const float4*)a.src[seg])[off];
  u16x4 r;
  r[0] = f2b(v.x); r[1] = f2b(v.y); r[2] = f2b(v.z); r[3] = f2b(v.w);
  ((u16x4*)a.dst[seg])[off] = r;
}

// ---------------------------------------------------------------------------
// GEMM: C[M,N] = act( X[M,K] @ W[N,K]^T ), bf16 in, fp32 accum.
// OMODE: 0 = normal store, 1 = normal + transposed bf16 aux, 2 = transposed only.
// Transposed layout: T[((b*H + col>>7)*R + (col&127))*N_ + (row&4095)]  (needs N==E_).
// ---------------------------------------------------------------------------
template<int ACT, int OMODE, typename OutT>
__global__ void __launch_bounds__(256) gemm_bt(const u16* __restrict__ X, const u16* __restrict__ W,
                                               OutT* __restrict__ C, u16* __restrict__ T,
                                               int M, int N, int K) {
  __shared__ u16 As[128 * 32];
  __shared__ u16 Bs[128 * 32];
  const int m0 = blockIdx.x * 128;
  const int n0 = blockIdx.y * 128;
  const int tid = threadIdx.x;
  const int wave = tid >> 6;
  const int lane = tid & 63;
  const int wr = wave >> 1, wc = wave & 1;

  const u16* Ap = X + (size_t)(m0 + wave * 32 + (lane >> 2)) * K + (lane & 3) * 8;
  const u16* Bp = W + (size_t)(n0 + wave * 32 + (lane >> 2)) * K + (lane & 3) * 8;
  u16* AsW = As + wave * 32 * 32;
  u16* BsW = Bs + wave * 32 * 32;

  f32x4 acc[4][4];
#pragma unroll
  for (int i = 0; i < 4; i++)
#pragma unroll
    for (int j = 0; j < 4; j++) acc[i][j] = (f32x4){0.f, 0.f, 0.f, 0.f};

  for (int k0 = 0; k0 < K; k0 += 32) {
    __builtin_amdgcn_global_load_lds((const __attribute__((address_space(1))) unsigned int*)(Ap + k0),
                                     (__attribute__((address_space(3))) unsigned int*)(AsW), 16, 0, 0);
    __builtin_amdgcn_global_load_lds((const __attribute__((address_space(1))) unsigned int*)(Ap + 16 * (size_t)K + k0),
                                     (__attribute__((address_space(3))) unsigned int*)(AsW + 16 * 32), 16, 0, 0);
    __builtin_amdgcn_global_load_lds((const __attribute__((address_space(1))) unsigned int*)(Bp + k0),
                                     (__attribute__((address_space(3))) unsigned int*)(BsW), 16, 0, 0);
    __builtin_amdgcn_global_load_lds((const __attribute__((address_space(1))) unsigned int*)(Bp + 16 * (size_t)K + k0),
                                     (__attribute__((address_space(3))) unsigned int*)(BsW + 16 * 32), 16, 0, 0);
    __syncthreads();
    bf16x8 af[4], bfr[4];
#pragma unroll
    for (int mi = 0; mi < 4; mi++)
      af[mi] = *(const bf16x8*)&As[(wr * 64 + mi * 16 + (lane & 15)) * 32 + (lane >> 4) * 8];
#pragma unroll
    for (int ni = 0; ni < 4; ni++)
      bfr[ni] = *(const bf16x8*)&Bs[(wc * 64 + ni * 16 + (lane & 15)) * 32 + (lane >> 4) * 8];
#pragma unroll
    for (int mi = 0; mi < 4; mi++)
#pragma unroll
      for (int ni = 0; ni < 4; ni++)
        acc[mi][ni] = __builtin_amdgcn_mfma_f32_16x16x32_bf16(af[mi], bfr[ni], acc[mi][ni], 0, 0, 0);
    __syncthreads();
  }
#pragma unroll
  for (int mi = 0; mi < 4; mi++) {
#pragma unroll
    for (int ni = 0; ni < 4; ni++) {
      int col = n0 + wc * 64 + ni * 16 + (lane & 15);
      int rbase = m0 + wr * 64 + mi * 16 + (lane >> 4) * 4;
      float vv[4];
#pragma unroll
      for (int r = 0; r < 4; r++) {
        float v = acc[mi][ni][r];
        if (ACT == 1) v = v * sigm(v);
        else if (ACT == 2) v = sigm(v);
        vv[r] = v;
      }
      if constexpr (OMODE != 2) {
#pragma unroll
        for (int r = 0; r < 4; r++) {
          size_t idx = (size_t)(rbase + r) * N + col;
          if constexpr (sizeof(OutT) == 2) C[idx] = f2b(vv[r]);
          else C[idx] = vv[r];
        }
      }
      if constexpr (OMODE != 0) {
        int bb = rbase >> 12;
        int n = rbase & (N_ - 1);
        size_t tidx = ((size_t)(bb * H_ + (col >> 7)) * R_ + (col & (R_ - 1))) * N_ + n;
        u16x4 pk;
#pragma unroll
        for (int r = 0; r < 4; r++) pk[r] = f2b(vv[r]);
        *(u16x4*)&T[tidx] = pk;
      }
    }
  }
}

// ---------------------------------------------------------------------------
// f = x @ Wf^T  ->  log_f[b,h,n] = log(lb_h + (1-lb_h)*sigmoid(f))
// ---------------------------------------------------------------------------
__global__ void __launch_bounds__(256) logf_proj(const u16* __restrict__ x, const u16* __restrict__ Wf,
                                                 const float* __restrict__ llb, float* __restrict__ LOGF) {
  int row = blockIdx.x * 4 + (threadIdx.x >> 6);
  int lane = threadIdx.x & 63;
  const u16* xr = x + (size_t)row * E_ + lane * 16;
  u16x8 xa = *(const u16x8*)xr;
  u16x8 xb = *(const u16x8*)(xr + 8);
  float xv[16];
#pragma unroll
  for (int i = 0; i < 8; i++) { xv[i] = b2f(xa[i]); xv[8 + i] = b2f(xb[i]); }
  int b = row >> 12, n = row & (N_ - 1);
#pragma unroll
  for (int h = 0; h < H_; h++) {
    const u16* wr = Wf + (size_t)h * E_ + lane * 16;
    u16x8 wa = *(const u16x8*)wr;
    u16x8 wb = *(const u16x8*)(wr + 8);
    float s = 0.f;
#pragma unroll
    for (int i = 0; i < 8; i++) s += xv[i] * b2f(wa[i]) + xv[8 + i] * b2f(wb[i]);
#pragma unroll
    for (int m = 1; m < 64; m <<= 1) s += __shfl_xor(s, m);
    if (lane == h) {
      float lb = expf(llb[h]);
      float fg = lb + (1.f - lb) * sigm(s);
      LOGF[(size_t)(b * H_ + h) * N_ + n] = logf(fg);
    }
  }
}

// ---------------------------------------------------------------------------
// Householder on bf16 q: q = (q - 2*(q.b)/(|b|^2+1e-12)*b) * R^-0.5 (in place)
// ---------------------------------------------------------------------------
__global__ void __launch_bounds__(256) householder(u16* __restrict__ Q, const u16* __restrict__ BETA) {
  int row = blockIdx.x;
  int tid = threadIdx.x;
  u16* q = Q + (size_t)row * E_;
  const u16* bt = BETA + (size_t)row * E_;
  u16x4 q4 = *(const u16x4*)(q + tid * 4);
  u16x4 b4 = *(const u16x4*)(bt + tid * 4);
  float qv[4], bv[4];
#pragma unroll
  for (int i = 0; i < 4; i++) { qv[i] = b2f(q4[i]); bv[i] = b2f(b4[i]); }
  float ss = bv[0]*bv[0] + bv[1]*bv[1] + bv[2]*bv[2] + bv[3]*bv[3];
  float qd = qv[0]*bv[0] + qv[1]*bv[1] + qv[2]*bv[2] + qv[3]*bv[3];
  __shared__ float red[8];
#pragma unroll
  for (int m = 1; m < 64; m <<= 1) { ss += __shfl_xor(ss, m); qd += __shfl_xor(qd, m); }
  int wid = tid >> 6;
  if ((tid & 63) == 0) { red[wid] = ss; red[4 + wid] = qd; }
  __syncthreads();
  ss = red[0] + red[1] + red[2] + red[3];
  qd = red[4] + red[5] + red[6] + red[7];
  float coef = 2.f * qd / (ss + 1e-12f);
  const float scale = 0.08838834764831845f;  // 128^-0.5 folded in
  u16x4 o4;
#pragma unroll
  for (int i = 0; i < 4; i++) o4[i] = f2b((qv[i] - coef * bv[i]) * scale);
  *(u16x4*)(q + tid * 4) = o4;
}

// inclusive scan of the 128 log-decay values of one chunk into cum[] (wave 0)
__device__ __forceinline__ void scan_chunk(const float* __restrict__ lf, float* cum, int tid) {
  if (tid < 64) {
    float a = lf[tid], b = lf[tid + 64];
#pragma unroll
    for (int off = 1; off < 64; off <<= 1) {
      float t = __shfl_up(a, off);  if (tid >= off) a += t;
      float t2 = __shfl_up(b, off); if (tid >= off) b += t2;
    }
    b += __shfl(a, 63);
    cum[tid] = a; cum[tid + 64] = b;
  }
  __syncthreads();
}

// stage a [128 x 32] bf16 slab (row stride `stride` elements) into LDS [128][40]
__device__ __forceinline__ void stage32(u16* dst, const u16* src, size_t stride, int tid) {
  int r0 = tid >> 2, c8 = (tid & 3) * 8;
  *(u16x8*)&dst[(size_t)r0 * 40 + c8] = *(const u16x8*)&src[(size_t)r0 * stride + c8];
  int r1 = r0 + 64;
  *(u16x8*)&dst[(size_t)r1 * 40 + c8] = *(const u16x8*)&src[(size_t)r1 * stride + c8];
}

// same, scaling column j (slab-local) by w[j0 + j]
__device__ __forceinline__ void stage32_scaled(u16* dst, const u16* src, size_t stride,
                                               const float* w, int j0, int tid) {
  int c8 = (tid & 3) * 8;
  float wv[8];
#pragma unroll
  for (int i = 0; i < 8; i++) wv[i] = w[j0 + c8 + i];
#pragma unroll
  for (int rr = 0; rr < 128; rr += 64) {
    int r = rr + (tid >> 2);
    u16x8 raw = *(const u16x8*)&src[(size_t)r * stride + c8];
    u16x8 o;
#pragma unroll
    for (int i = 0; i < 8; i++) o[i] = f2b(b2f(raw[i]) * wv[i]);
    *(u16x8*)&dst[(size_t)r * 40 + c8] = o;
  }
}

// one K=32 MFMA step over a 128x128 output (4 waves, 64x64 each), A/B slabs in LDS [128][40]
__device__ __forceinline__ void mfma16(f32x4 (&acc)[4][4], const u16* A, const u16* Bm,
                                       int wr, int wc, int l15, int q8) {
  bf16x8 af[4], bf[4];
#pragma unroll
  for (int mi = 0; mi < 4; mi++) af[mi] = *(const bf16x8*)&A[(wr * 64 + mi * 16 + l15) * 40 + q8];
#pragma unroll
  for (int ni = 0; ni < 4; ni++) bf[ni] = *(const bf16x8*)&Bm[(wc * 64 + ni * 16 + l15) * 40 + q8];
#pragma unroll
  for (int mi = 0; mi < 4; mi++)
#pragma unroll
    for (int ni = 0; ni < 4; ni++)
      acc[mi][ni] = __builtin_amdgcn_mfma_f32_16x16x32_bf16(af[mi], bf[ni], acc[mi][ni], 0, 0, 0);
}

// ---------------------------------------------------------------------------
// Phase A (MFMA): UT[v][k] = sum_j VT[v][j] * (w_j * KT[k][j]),  w_j=exp(cumC-cum_j)
// ---------------------------------------------------------------------------
__global__ void __launch_bounds__(256) gla_phaseA(const u16* __restrict__ KT, const u16* __restrict__ VT,
                                                  const float* __restrict__ LOGF,
                                                  float* __restrict__ U, float* __restrict__ DC) {
  const int blk = blockIdx.x;
  const int bh = blk >> 5, c = blk & 31;
  const int tid = threadIdx.x;
  const int wave = tid >> 6, lane = tid & 63;
  const int wr = wave >> 1, wc = wave & 1, l15 = lane & 15, q8 = (lane >> 4) * 8;
  __shared__ u16 SA[128 * 40];
  __shared__ u16 SB[128 * 40];
  __shared__ float cum[CHUNK_];
  __shared__ float wd[CHUNK_];
  scan_chunk(LOGF + (size_t)bh * N_ + c * CHUNK_, cum, tid);
  if (tid < 128) wd[tid] = expf(cum[127] - cum[tid]);
  __syncthreads();
  const u16* vbase = VT + ((size_t)bh * R_) * N_ + (size_t)c * CHUNK_;
  const u16* kbase = KT + ((size_t)bh * R_) * N_ + (size_t)c * CHUNK_;
  f32x4 acc[4][4];
#pragma unroll
  for (int i = 0; i < 4; i++)
#pragma unroll
    for (int j = 0; j < 4; j++) acc[i][j] = (f32x4){0.f, 0.f, 0.f, 0.f};
  for (int j0 = 0; j0 < CHUNK_; j0 += 32) {
    __syncthreads();
    stage32(SA, vbase + j0, N_, tid);
    stage32_scaled(SB, kbase + j0, N_, wd, j0, tid);
    __syncthreads();
    mfma16(acc, SA, SB, wr, wc, l15, q8);
  }
  float* Up = U + (size_t)blk * (R_ * R_);
#pragma unroll
  for (int mi = 0; mi < 4; mi++) {
#pragma unroll
    for (int ni = 0; ni < 4; ni++) {
      int v = wr * 64 + mi * 16 + (lane >> 4) * 4;
      int k = wc * 64 + ni * 16 + l15;
#pragma unroll
      for (int r = 0; r < 4; r++) Up[(size_t)(v + r) * R_ + k] = acc[mi][ni][r];
    }
  }
  if (tid == 0) DC[blk] = expf(cum[127]);
}

// ---------------------------------------------------------------------------
// Phase B: propagate chunk-start states; U fp32 [v][k] -> SS bf16 [v][k]
// ---------------------------------------------------------------------------
__global__ void __launch_bounds__(256) gla_phaseB(const float* __restrict__ U, const float* __restrict__ DC,
                                                  u16* __restrict__ SSb) {
  int idx = blockIdx.x * 256 + threadIdx.x;
  int bh = idx >> 14;
  int e = idx & 16383;
  float s = 0.f;
  for (int c = 0; c < NC_; c++) {
    size_t off = ((size_t)bh * NC_ + c) * 16384 + e;
    SSb[off] = f2b(s);
    s = DC[bh * NC_ + c] * s + U[off];
  }
}

// ---------------------------------------------------------------------------
// Phase C (MFMA): o_i = exp(cum_i)*q_i@Sstart + sum_{j<=i} exp(cum_i-cum_j)(q_i.k_j) v_j
// Step 1: S^T = K@Q^T (rows j, cols i)  -> mask+decay -> Ps[i][j] bf16 (u16x4 writes)
// Step 2: acc = Q@SS^T (rows i, cols v) -> scale rows by exp(cum_i)
// Step 3: acc += Ps@V^T  (A-frags straight from Ps; waves with i<64 skip j>=64 slabs)
// ---------------------------------------------------------------------------
__global__ void __launch_bounds__(256) gla_phaseC(const u16* __restrict__ Qb, const u16* __restrict__ Kb,
                                                  const u16* __restrict__ VT, const u16* __restrict__ SSb,
                                                  const float* __restrict__ LOGF, u16* __restrict__ Ob) {
  const int blk = blockIdx.x;
  const int bh = blk >> 5, c = blk & 31;
  const int b = bh >> 3, h = bh & 7;
  const int tid = threadIdx.x;
  const int wave = tid >> 6, lane = tid & 63;
  const int wr = wave >> 1, wc = wave & 1, l15 = lane & 15;
  const int q4i = (lane >> 4) * 4, q8 = (lane >> 4) * 8;
  __shared__ u16 SA[128 * 40];
  __shared__ u16 SB[128 * 40];
  __shared__ u16 Ps[128 * 136];
  __shared__ float cum[CHUNK_];
  __shared__ float cumE[CHUNK_];
  scan_chunk(LOGF + (size_t)bh * N_ + c * CHUNK_, cum, tid);
  if (tid < 128) cumE[tid] = expf(cum[tid]);
  __syncthreads();
  const size_t rowbase = ((size_t)(b * N_ + c * CHUNK_)) * E_ + (size_t)h * R_;
  const u16* vtbase = VT + ((size_t)bh * R_) * N_ + (size_t)c * CHUNK_;
  const u16* ssbase = SSb + (size_t)blk * (R_ * R_);

  f32x4 acc[4][4];
#pragma unroll
  for (int i = 0; i < 4; i++)
#pragma unroll
    for (int j = 0; j < 4; j++) acc[i][j] = (f32x4){0.f, 0.f, 0.f, 0.f};

  // ---- S^T = K @ Q^T ----
  for (int r0 = 0; r0 < R_; r0 += 32) {
    __syncthreads();
    stage32(SA, Kb + rowbase + r0, E_, tid);   // rows j
    stage32(SB, Qb + rowbase + r0, E_, tid);   // rows i
    __syncthreads();
    mfma16(acc, SA, SB, wr, wc, l15, q8);
  }
  // ---- mask + decay -> Ps[i][j] ----
#pragma unroll
  for (int mi = 0; mi < 4; mi++) {
#pragma unroll
    for (int ni = 0; ni < 4; ni++) {
      int jb = wr * 64 + mi * 16 + q4i;
      int i = wc * 64 + ni * 16 + l15;
      float ci = cum[i];
      float4 cj = *(const float4*)&cum[jb];
      u16x4 pk;
      float cjv[4] = {cj.x, cj.y, cj.z, cj.w};
#pragma unroll
      for (int r = 0; r < 4; r++) {
        int j = jb + r;
        float w = (j <= i) ? expf(ci - cjv[r]) : 0.f;
        pk[r] = f2b(acc[mi][ni][r] * w);
      }
      *(u16x4*)&Ps[i * 136 + jb] = pk;
    }
  }
  // ---- term1: Q @ SS^T ----
#pragma unroll
  for (int i = 0; i < 4; i++)
#pragma unroll
    for (int j = 0; j < 4; j++) acc[i][j] = (f32x4){0.f, 0.f, 0.f, 0.f};
  for (int k0 = 0; k0 < R_; k0 += 32) {
    __syncthreads();   // also guards Ps writes complete (1st iter) / SB reads done
    stage32(SA, Qb + rowbase + k0, E_, tid);     // rows i
    stage32(SB, ssbase + k0, R_, tid);           // rows v (SS^T layout [v][k])
    __syncthreads();
    mfma16(acc, SA, SB, wr, wc, l15, q8);
  }
  // scale rows by exp(cum_i)
#pragma unroll
  for (int mi = 0; mi < 4; mi++) {
    float4 e4 = *(const float4*)&cumE[wr * 64 + mi * 16 + q4i];
    float ev[4] = {e4.x, e4.y, e4.z, e4.w};
#pragma unroll
    for (int ni = 0; ni < 4; ni++)
#pragma unroll
      for (int r = 0; r < 4; r++) acc[mi][ni][r] *= ev[r];
  }
  // ---- term2: acc += P @ V^T ----
  for (int j0 = 0; j0 < CHUNK_; j0 += 32) {
    __syncthreads();
    stage32(SB, vtbase + j0, N_, tid);           // rows v
    __syncthreads();
    if (wr == 1 || j0 < 64) {                    // wr==0 waves: j>=64 all masked
      bf16x8 af[4], bf[4];
#pragma unroll
      for (int mi = 0; mi < 4; mi++)
        af[mi] = *(const bf16x8*)&Ps[(wr * 64 + mi * 16 + l15) * 136 + j0 + q8];
#pragma unroll
      for (int ni = 0; ni < 4; ni++)
        bf[ni] = *(const bf16x8*)&SB[(wc * 64 + ni * 16 + l15) * 40 + q8];
#pragma unroll
      for (int mi = 0; mi < 4; mi++)
#pragma unroll
        for (int ni = 0; ni < 4; ni++)
          acc[mi][ni] = __builtin_amdgcn_mfma_f32_16x16x32_bf16(af[mi], bf[ni], acc[mi][ni], 0, 0, 0);
    }
  }
  // ---- write O (bf16, row-major [m][E]) ----
#pragma unroll
  for (int mi = 0; mi < 4; mi++) {
#pragma unroll
    for (int ni = 0; ni < 4; ni++) {
      int i = wr * 64 + mi * 16 + q4i;
      int v = wc * 64 + ni * 16 + l15;
#pragma unroll
      for (int r = 0; r < 4; r++)
        Ob[rowbase + (size_t)(i + r) * E_ + v] = f2b(acc[mi][ni][r]);
    }
  }
}

// ---------------------------------------------------------------------------
// o = o * gate (both bf16); LayerNorm(weight-only, fp32 gamma) -> bf16
// ---------------------------------------------------------------------------
__global__ void __launch_bounds__(256) gate_ln(const u16* __restrict__ O, const u16* __restrict__ G,
                                               const float* __restrict__ gamma, u16* __restrict__ OLN) {
  int row = blockIdx.x, tid = threadIdx.x;
  u16x4 o4 = *(const u16x4*)(O + (size_t)row * E_ + tid * 4);
  u16x4 g4 = *(const u16x4*)(G + (size_t)row * E_ + tid * 4);
  float x0 = b2f(o4[0]) * b2f(g4[0]), x1 = b2f(o4[1]) * b2f(g4[1]);
  float x2 = b2f(o4[2]) * b2f(g4[2]), x3 = b2f(o4[3]) * b2f(g4[3]);
  float s = x0 + x1 + x2 + x3;
  float sq = x0 * x0 + x1 * x1 + x2 * x2 + x3 * x3;
  __shared__ float red[8];
#pragma unroll
  for (int m = 1; m < 64; m <<= 1) { s += __shfl_xor(s, m); sq += __shfl_xor(sq, m); }
  int wid = tid >> 6;
  if ((tid & 63) == 0) { red[wid] = s; red[4 + wid] = sq; }
  __syncthreads();
  s = red[0] + red[1] + red[2] + red[3];
  sq = red[4] + red[5] + red[6] + red[7];
  float mu = s * (1.f / 1024.f);
  float var = sq * (1.f / 1024.f) - mu * mu;
  float rs = rsqrtf(var + 1e-5f);
  int e = tid * 4;
  u16x4 r4;
  r4[0] = f2b((x0 - mu) * rs * gamma[e + 0]);
  r4[1] = f2b((x1 - mu) * rs * gamma[e + 1]);
  r4[2] = f2b((x2 - mu) * rs * gamma[e + 2]);
  r4[3] = f2b((x3 - mu) * rs * gamma[e + 3]);
  *(u16x4*)(OLN + (size_t)row * E_ + e) = r4;
}

// ---------------------------------------------------------------------------
extern "C" void kernel_launch(void* const* d_in, const int* in_sizes, int n_in,
                              void* d_out, int out_size, void* d_ws, size_t ws_size,
                              hipStream_t stream) {
  (void)in_sizes; (void)n_in; (void)out_size; (void)ws_size;
  const float* x   = (const float*)d_in[0];
  const float* llb = (const float*)d_in[1];
  const float* Wq  = (const float*)d_in[2];
  const float* Wk  = (const float*)d_in[3];
  const float* Wv  = (const float*)d_in[4];
  const float* Wf  = (const float*)d_in[5];
  const float* Wb1 = (const float*)d_in[6];
  const float* Wb2 = (const float*)d_in[7];
  const float* Wg1 = (const float*)d_in[8];
  const float* Wg2 = (const float*)d_in[9];
  const float* gm  = (const float*)d_in[10];
  const float* Wo  = (const float*)d_in[11];
  float* out = (float*)d_out;

  char* ws = (char*)d_ws;
  const size_t SZB = (size_t)M_ * E_ * 2;            // 16.78 MB bf16 [M,E]
  u16*   Qb    = (u16*)(ws + 0 * SZB);               // q bf16 (OLN overlays later)
  u16*   Kb    = (u16*)(ws + 1 * SZB);
  u16*   KT    = (u16*)(ws + 2 * SZB);               // [B,H,R,N]
  u16*   VT    = (u16*)(ws + 3 * SZB);               // [B,H,R,N]
  u16*   BETAb = (u16*)(ws + 4 * SZB);               // beta -> O overlay
  u16*   GATEb = (u16*)(ws + 5 * SZB);
  u16*   SSb   = (u16*)(ws + 6 * SZB);               // chunk-start states bf16 [v][k]
  u16*   XB    = (u16*)(ws + 7 * SZB);
  float* U     = (float*)(ws + 8 * SZB);             // fp32 [512][128][128]
  char*  tail  = ws + 8 * SZB + (size_t)BH_ * NC_ * R_ * R_ * 4;
  u16*   WQb   = (u16*)tail;
  u16*   WKb   = WQb + (size_t)E_ * E_;
  u16*   WVb   = WKb + (size_t)E_ * E_;
  u16*   WFb   = WVb + (size_t)E_ * E_;
  u16*   WB1b  = WFb + (size_t)H_ * E_;
  u16*   WB2b  = WB1b + (size_t)R_ * E_;
  u16*   WG1b  = WB2b + (size_t)E_ * R_;
  u16*   WG2b  = WG1b + (size_t)R_ * E_;
  u16*   WOb   = WG2b + (size_t)E_ * R_;
  u16*   T1    = WOb + (size_t)E_ * E_;              // [M,R] bf16
  float* LOGF  = (float*)(T1 + (size_t)M_ * R_);
  float* DC    = LOGF + (size_t)BH_ * N_;
  u16*   Ob    = BETAb;                              // overlay (beta dead)
  u16*   OLN   = Qb;                                 // overlay (q dead)
  // total ws ~185 MB

  CvtArgs ca;
  ca.src[0] = x;   ca.dst[0] = XB;
  ca.src[1] = Wq;  ca.dst[1] = WQb;
  ca.src[2] = Wk;  ca.dst[2] = WKb;
  ca.src[3] = Wv;  ca.dst[3] = WVb;
  ca.src[4] = Wf;  ca.dst[4] = WFb;
  ca.src[5] = Wb1; ca.dst[5] = WB1b;
  ca.src[6] = Wb2; ca.dst[6] = WB2b;
  ca.src[7] = Wg1; ca.dst[7] = WG1b;
  ca.src[8] = Wg2; ca.dst[8] = WG2b;
  ca.src[9] = Wo;  ca.dst[9] = WOb;

  dim3 blk(256);
  dim3 gBig(M_ / 128, E_ / 128);   // 64 x 8
  dim3 gT1(M_ / 128, 1);           // 64 x 1

  cvt_all<<<dim3(12808), blk, 0, stream>>>(ca);
  gemm_bt<1, 0, u16><<<gBig, blk, 0, stream>>>(XB, WQb, Qb, nullptr, M_, E_, E_);     // q=silu
  gemm_bt<1, 1, u16><<<gBig, blk, 0, stream>>>(XB, WKb, Kb, KT, M_, E_, E_);          // k=silu (+KT)
  gemm_bt<0, 2, u16><<<gBig, blk, 0, stream>>>(XB, WVb, nullptr, VT, M_, E_, E_);     // v (VT only)
  logf_proj<<<dim3(M_ / 4), blk, 0, stream>>>(XB, WFb, llb, LOGF);
  gemm_bt<0, 0, u16><<<gT1, blk, 0, stream>>>(XB, WB1b, T1, nullptr, M_, R_, E_);     // t1b
  gemm_bt<1, 0, u16><<<gBig, blk, 0, stream>>>(T1, WB2b, BETAb, nullptr, M_, E_, R_); // beta=silu
  householder<<<dim3(M_), blk, 0, stream>>>(Qb, BETAb);
  gemm_bt<0, 0, u16><<<gT1, blk, 0, stream>>>(XB, WG1b, T1, nullptr, M_, R_, E_);     // t1g
  gemm_bt<2, 0, u16><<<gBig, blk, 0, stream>>>(T1, WG2b, GATEb, nullptr, M_, E_, R_); // gate
  gla_phaseA<<<dim3(BH_ * NC_), blk, 0, stream>>>(KT, VT, LOGF, U, DC);
  gla_phaseB<<<dim3(BH_ * 16384 / 256), blk, 0, stream>>>(U, DC, SSb);
  gla_phaseC<<<dim3(BH_ * NC_), blk, 0, stream>>>(Qb, Kb, VT, SSb, LOGF, Ob);
  gate_ln<<<dim3(M_), blk, 0, stream>>>(Ob, GATEb, gm, OLN);
  gemm_bt<0, 0, float><<<gBig, blk, 0, stream>>>(OLN, WOb, out, nullptr, M_, E_, E_); // out fp32
}

// Round 4
// 343.528 us; speedup vs baseline: 1.4922x; 1.1819x over previous
//
#include <hip/hip_runtime.h>
#include <hip/hip_bf16.h>

using u16 = unsigned short;
typedef __attribute__((ext_vector_type(8))) short bf16x8;
typedef __attribute__((ext_vector_type(4))) float f32x4;
typedef __attribute__((ext_vector_type(8))) u16 u16x8;
typedef __attribute__((ext_vector_type(4))) u16 u16x4;

#define B_ 2
#define N_ 4096
#define E_ 1024
#define R_ 128
#define H_ 8
#define M_ 8192      // B*N
#define CHUNK_ 128
#define NC_ 32       // N/CHUNK
#define BH_ 16       // B*H

__device__ __forceinline__ float b2f(u16 u) { return __uint_as_float(((unsigned)u) << 16); }
__device__ __forceinline__ u16 f2b(float f) {
  unsigned u = __float_as_uint(f);
  return (u16)((u + 0x7fffu + ((u >> 16) & 1u)) >> 16);   // RNE
}
__device__ __forceinline__ float sigm(float x) { return 1.0f / (1.0f + expf(-x)); }

#define GLDS(g, l) __builtin_amdgcn_global_load_lds( \
    (const __attribute__((address_space(1))) unsigned int*)(g), \
    (__attribute__((address_space(3))) unsigned int*)(l), 16, 0, 0)

// ---------------------------------------------------------------------------
// fp32 -> bf16 conversion. Segments: x, Wq,Wk,Wv (into Wcat), Wf(into Wcat),
// Wb1,Wg1(into Wcat), Wb2/Wg2 (block-diagonal into Wcat2 + zero halves),
// Wo, and zero-fill of Wcat pad rows 3336-3455.
// ---------------------------------------------------------------------------
struct CvtArgs {
  const float* src[10];
  u16* dst[11];
};

__global__ void __launch_bounds__(256) cvt_all(CvtArgs a) {
  int idx = blockIdx.x * 256 + threadIdx.x;   // float4-granule index; grid exact
  const int SZ[11] = {2097152, 262144, 262144, 262144, 2048,
                      32768, 32768, 32768, 32768, 262144, 30720};
  int off = idx, seg = 0;
#pragma unroll
  for (int i = 0; i < 10; i++) {
    if (seg == i && off >= SZ[i]) { off -= SZ[i]; seg = i + 1; }
  }
  u16x4 z = (u16x4){0, 0, 0, 0};
  if (seg == 10) { ((u16x4*)a.dst[10])[off] = z; return; }   // Wcat pad rows
  float4 v = ((const float4*)a.src[seg])[off];
  u16x4 r;
  r[0] = f2b(v.x); r[1] = f2b(v.y); r[2] = f2b(v.z); r[3] = f2b(v.w);
  if (seg == 6) {              // Wb2 -> Wcat2 rows 0-1023, cols 0-127 (+zero cols 128-255)
    int n = off >> 5, c = off & 31;
    u16x4* W2 = (u16x4*)a.dst[6];
    W2[n * 64 + c] = r; W2[n * 64 + 32 + c] = z;
  } else if (seg == 8) {       // Wg2 -> Wcat2 rows 1024-2047, cols 128-255 (+zero cols 0-127)
    int n = off >> 5, c = off & 31;
    u16x4* W2 = (u16x4*)a.dst[8];
    W2[(1024 + n) * 64 + 32 + c] = r; W2[(1024 + n) * 64 + c] = z;
  } else {
    ((u16x4*)a.dst[seg])[off] = r;
  }
}

// ---------------------------------------------------------------------------
// Shared BK=64 GEMM K-loop: 128x128 block tile, two 32-wide panels per
// barrier pair (32 MFMA/barrier), global_load_lds width-16 staging.
// As/Bs: u16[8192] each (two [128][32] panels).
// ---------------------------------------------------------------------------
__device__ __forceinline__ void mfma_panel(f32x4 (&acc)[4][4], const u16* A, const u16* Bm,
                                           int wr, int wc, int l15, int q8) {
  bf16x8 af[4], bf[4];
#pragma unroll
  for (int mi = 0; mi < 4; mi++) af[mi] = *(const bf16x8*)&A[(wr * 64 + mi * 16 + l15) * 32 + q8];
#pragma unroll
  for (int ni = 0; ni < 4; ni++) bf[ni] = *(const bf16x8*)&Bm[(wc * 64 + ni * 16 + l15) * 32 + q8];
#pragma unroll
  for (int mi = 0; mi < 4; mi++)
#pragma unroll
    for (int ni = 0; ni < 4; ni++)
      acc[mi][ni] = __builtin_amdgcn_mfma_f32_16x16x32_bf16(af[mi], bf[ni], acc[mi][ni], 0, 0, 0);
}

__device__ __forceinline__ void gemm_loop(const u16* __restrict__ X, const u16* __restrict__ W,
                                          int m0, int n0, int K,
                                          u16* As, u16* Bs, f32x4 (&acc)[4][4], int tid) {
  const int wave = tid >> 6, lane = tid & 63;
  const int wr = wave >> 1, wc = wave & 1, l15 = lane & 15, q8 = (lane >> 4) * 8;
  const u16* Ap = X + (size_t)(m0 + wave * 32 + (lane >> 2)) * K + (lane & 3) * 8;
  const u16* Bp = W + (size_t)(n0 + wave * 32 + (lane >> 2)) * K + (lane & 3) * 8;
  u16* A0 = As + wave * 1024;
  u16* B0 = Bs + wave * 1024;
  for (int k0 = 0; k0 < K; k0 += 64) {
    GLDS(Ap + k0,                    A0);
    GLDS(Ap + 16 * (size_t)K + k0,   A0 + 512);
    GLDS(Ap + k0 + 32,               A0 + 4096);
    GLDS(Ap + 16 * (size_t)K + k0 + 32, A0 + 4608);
    GLDS(Bp + k0,                    B0);
    GLDS(Bp + 16 * (size_t)K + k0,   B0 + 512);
    GLDS(Bp + k0 + 32,               B0 + 4096);
    GLDS(Bp + 16 * (size_t)K + k0 + 32, B0 + 4608);
    __syncthreads();
    mfma_panel(acc, As, Bs, wr, wc, l15, q8);
    mfma_panel(acc, As + 4096, Bs + 4096, wr, wc, l15, q8);
    __syncthreads();
  }
}

// ---------------------------------------------------------------------------
// Mega-GEMM: X[M,1024] @ Wcat[3456,1024]^T. Per-block-column epilogue:
//  ny 0-7   : silu -> Qb
//  ny 8-15  : silu -> Kb + transposed KT[b,h,r,n]
//  ny 16-23 : -> transposed VT only
//  ny 24-25 : -> T1[M,256]
//  ny 26    : cols 3328-3335 = f logits -> LOGF = log(lb + (1-lb)*sigmoid(f))
// ---------------------------------------------------------------------------
__global__ void __launch_bounds__(256) mega_gemm(const u16* __restrict__ X, const u16* __restrict__ Wcat,
                                                 const float* __restrict__ llb,
                                                 u16* __restrict__ Qb, u16* __restrict__ Kb,
                                                 u16* __restrict__ KT, u16* __restrict__ VT,
                                                 u16* __restrict__ T1, float* __restrict__ LOGF) {
  __shared__ u16 As[8192];
  __shared__ u16 Bs[8192];
  const int tid = threadIdx.x;
  const int m0 = blockIdx.x * 128;
  const int ny = blockIdx.y, n0 = ny * 128;
  f32x4 acc[4][4];
#pragma unroll
  for (int i = 0; i < 4; i++)
#pragma unroll
    for (int j = 0; j < 4; j++) acc[i][j] = (f32x4){0.f, 0.f, 0.f, 0.f};
  gemm_loop(X, Wcat, m0, n0, 1024, As, Bs, acc, tid);

  const int wave = tid >> 6, lane = tid & 63;
  const int wr = wave >> 1, wc = wave & 1, l15 = lane & 15, q4 = (lane >> 4) * 4;
#pragma unroll
  for (int mi = 0; mi < 4; mi++) {
#pragma unroll
    for (int ni = 0; ni < 4; ni++) {
      int col = n0 + wc * 64 + ni * 16 + l15;
      int rbase = m0 + wr * 64 + mi * 16 + q4;
      float vv[4];
#pragma unroll
      for (int r = 0; r < 4; r++) vv[r] = acc[mi][ni][r];
      if (ny < 16) {
#pragma unroll
        for (int r = 0; r < 4; r++) vv[r] = vv[r] * sigm(vv[r]);
      }
      if (ny < 8) {
#pragma unroll
        for (int r = 0; r < 4; r++) Qb[(size_t)(rbase + r) * E_ + col] = f2b(vv[r]);
      } else if (ny < 16) {
        int ck = col - 1024;
#pragma unroll
        for (int r = 0; r < 4; r++) Kb[(size_t)(rbase + r) * E_ + ck] = f2b(vv[r]);
        int bb = rbase >> 12, n = rbase & (N_ - 1);
        size_t tidx = ((size_t)(bb * H_ + (ck >> 7)) * R_ + (ck & (R_ - 1))) * N_ + n;
        u16x4 pk;
#pragma unroll
        for (int r = 0; r < 4; r++) pk[r] = f2b(vv[r]);
        *(u16x4*)&KT[tidx] = pk;
      } else if (ny < 24) {
        int cv = col - 2048;
        int bb = rbase >> 12, n = rbase & (N_ - 1);
        size_t tidx = ((size_t)(bb * H_ + (cv >> 7)) * R_ + (cv & (R_ - 1))) * N_ + n;
        u16x4 pk;
#pragma unroll
        for (int r = 0; r < 4; r++) pk[r] = f2b(vv[r]);
        *(u16x4*)&VT[tidx] = pk;
      } else if (ny < 26) {
        int ct = col - 3072;
#pragma unroll
        for (int r = 0; r < 4; r++) T1[(size_t)(rbase + r) * 256 + ct] = f2b(vv[r]);
      } else if (wc == 0 && ni == 0 && l15 < 8) {
        int h = l15, bb = rbase >> 12, n = rbase & (N_ - 1);
        float lb = expf(llb[h]);
        float4 o;
        o.x = logf(lb + (1.f - lb) * sigm(vv[0]));
        o.y = logf(lb + (1.f - lb) * sigm(vv[1]));
        o.z = logf(lb + (1.f - lb) * sigm(vv[2]));
        o.w = logf(lb + (1.f - lb) * sigm(vv[3]));
        *(float4*)&LOGF[(size_t)(bb * H_ + h) * N_ + n] = o;
      }
    }
  }
}

// ---------------------------------------------------------------------------
// beta+gate GEMM: T1[M,256] @ Wcat2[2048,256]^T (block-diagonal).
// cols 0-1023 -> silu -> BETA; cols 1024-2047 -> sigmoid -> GATE.
// ---------------------------------------------------------------------------
__global__ void __launch_bounds__(256) bg_gemm(const u16* __restrict__ T1, const u16* __restrict__ W2,
                                               u16* __restrict__ BETA, u16* __restrict__ GATE) {
  __shared__ u16 As[8192];
  __shared__ u16 Bs[8192];
  const int tid = threadIdx.x;
  const int m0 = blockIdx.x * 128;
  const int n0 = blockIdx.y * 128;
  f32x4 acc[4][4];
#pragma unroll
  for (int i = 0; i < 4; i++)
#pragma unroll
    for (int j = 0; j < 4; j++) acc[i][j] = (f32x4){0.f, 0.f, 0.f, 0.f};
  gemm_loop(T1, W2, m0, n0, 256, As, Bs, acc, tid);
  const int wave = tid >> 6, lane = tid & 63;
  const int wr = wave >> 1, wc = wave & 1, l15 = lane & 15, q4 = (lane >> 4) * 4;
#pragma unroll
  for (int mi = 0; mi < 4; mi++) {
#pragma unroll
    for (int ni = 0; ni < 4; ni++) {
      int col = n0 + wc * 64 + ni * 16 + l15;
      int rbase = m0 + wr * 64 + mi * 16 + q4;
      if (col < 1024) {
#pragma unroll
        for (int r = 0; r < 4; r++) {
          float v = acc[mi][ni][r];
          BETA[(size_t)(rbase + r) * E_ + col] = f2b(v * sigm(v));
        }
      } else {
#pragma unroll
        for (int r = 0; r < 4; r++)
          GATE[(size_t)(rbase + r) * E_ + col - 1024] = f2b(sigm(acc[mi][ni][r]));
      }
    }
  }
}

// ---------------------------------------------------------------------------
// Output GEMM: OLN[M,1024] @ Wo[1024,1024]^T -> fp32 out.
// ---------------------------------------------------------------------------
__global__ void __launch_bounds__(256) out_gemm(const u16* __restrict__ X, const u16* __restrict__ W,
                                                float* __restrict__ C) {
  __shared__ u16 As[8192];
  __shared__ u16 Bs[8192];
  const int tid = threadIdx.x;
  const int m0 = blockIdx.x * 128;
  const int n0 = blockIdx.y * 128;
  f32x4 acc[4][4];
#pragma unroll
  for (int i = 0; i < 4; i++)
#pragma unroll
    for (int j = 0; j < 4; j++) acc[i][j] = (f32x4){0.f, 0.f, 0.f, 0.f};
  gemm_loop(X, W, m0, n0, 1024, As, Bs, acc, tid);
  const int wave = tid >> 6, lane = tid & 63;
  const int wr = wave >> 1, wc = wave & 1, l15 = lane & 15, q4 = (lane >> 4) * 4;
#pragma unroll
  for (int mi = 0; mi < 4; mi++) {
#pragma unroll
    for (int ni = 0; ni < 4; ni++) {
      int col = n0 + wc * 64 + ni * 16 + l15;
      int rbase = m0 + wr * 64 + mi * 16 + q4;
#pragma unroll
      for (int r = 0; r < 4; r++)
        C[(size_t)(rbase + r) * E_ + col] = acc[mi][ni][r];
    }
  }
}

// ---------------------------------------------------------------------------
// Householder on bf16 q (in place)
// ---------------------------------------------------------------------------
__global__ void __launch_bounds__(256) householder(u16* __restrict__ Q, const u16* __restrict__ BETA) {
  int row = blockIdx.x;
  int tid = threadIdx.x;
  u16* q = Q + (size_t)row * E_;
  const u16* bt = BETA + (size_t)row * E_;
  u16x4 q4 = *(const u16x4*)(q + tid * 4);
  u16x4 b4 = *(const u16x4*)(bt + tid * 4);
  float qv[4], bv[4];
#pragma unroll
  for (int i = 0; i < 4; i++) { qv[i] = b2f(q4[i]); bv[i] = b2f(b4[i]); }
  float ss = bv[0]*bv[0] + bv[1]*bv[1] + bv[2]*bv[2] + bv[3]*bv[3];
  float qd = qv[0]*bv[0] + qv[1]*bv[1] + qv[2]*bv[2] + qv[3]*bv[3];
  __shared__ float red[8];
#pragma unroll
  for (int m = 1; m < 64; m <<= 1) { ss += __shfl_xor(ss, m); qd += __shfl_xor(qd, m); }
  int wid = tid >> 6;
  if ((tid & 63) == 0) { red[wid] = ss; red[4 + wid] = qd; }
  __syncthreads();
  ss = red[0] + red[1] + red[2] + red[3];
  qd = red[4] + red[5] + red[6] + red[7];
  float coef = 2.f * qd / (ss + 1e-12f);
  const float scale = 0.08838834764831845f;  // 128^-0.5 folded in
  u16x4 o4;
#pragma unroll
  for (int i = 0; i < 4; i++) o4[i] = f2b((qv[i] - coef * bv[i]) * scale);
  *(u16x4*)(q + tid * 4) = o4;
}

// inclusive scan of the 128 log-decay values of one chunk into cum[] (wave 0)
__device__ __forceinline__ void scan_chunk(const float* __restrict__ lf, float* cum, int tid) {
  if (tid < 64) {
    float a = lf[tid], b = lf[tid + 64];
#pragma unroll
    for (int off = 1; off < 64; off <<= 1) {
      float t = __shfl_up(a, off);  if (tid >= off) a += t;
      float t2 = __shfl_up(b, off); if (tid >= off) b += t2;
    }
    b += __shfl(a, 63);
    cum[tid] = a; cum[tid + 64] = b;
  }
  __syncthreads();
}

// stage a [128 x 32] bf16 slab (row stride `stride` elements) into LDS [128][40]
__device__ __forceinline__ void stage32(u16* dst, const u16* src, size_t stride, int tid) {
  int r0 = tid >> 2, c8 = (tid & 3) * 8;
  *(u16x8*)&dst[(size_t)r0 * 40 + c8] = *(const u16x8*)&src[(size_t)r0 * stride + c8];
  int r1 = r0 + 64;
  *(u16x8*)&dst[(size_t)r1 * 40 + c8] = *(const u16x8*)&src[(size_t)r1 * stride + c8];
}

// same, scaling column j (slab-local) by w[j0 + j]
__device__ __forceinline__ void stage32_scaled(u16* dst, const u16* src, size_t stride,
                                               const float* w, int j0, int tid) {
  int c8 = (tid & 3) * 8;
  float wv[8];
#pragma unroll
  for (int i = 0; i < 8; i++) wv[i] = w[j0 + c8 + i];
#pragma unroll
  for (int rr = 0; rr < 128; rr += 64) {
    int r = rr + (tid >> 2);
    u16x8 raw = *(const u16x8*)&src[(size_t)r * stride + c8];
    u16x8 o;
#pragma unroll
    for (int i = 0; i < 8; i++) o[i] = f2b(b2f(raw[i]) * wv[i]);
    *(u16x8*)&dst[(size_t)r * 40 + c8] = o;
  }
}

// one K=32 MFMA step over a 128x128 output (4 waves), A/B slabs in LDS [128][40]
__device__ __forceinline__ void mfma16(f32x4 (&acc)[4][4], const u16* A, const u16* Bm,
                                       int wr, int wc, int l15, int q8) {
  bf16x8 af[4], bf[4];
#pragma unroll
  for (int mi = 0; mi < 4; mi++) af[mi] = *(const bf16x8*)&A[(wr * 64 + mi * 16 + l15) * 40 + q8];
#pragma unroll
  for (int ni = 0; ni < 4; ni++) bf[ni] = *(const bf16x8*)&Bm[(wc * 64 + ni * 16 + l15) * 40 + q8];
#pragma unroll
  for (int mi = 0; mi < 4; mi++)
#pragma unroll
    for (int ni = 0; ni < 4; ni++)
      acc[mi][ni] = __builtin_amdgcn_mfma_f32_16x16x32_bf16(af[mi], bf[ni], acc[mi][ni], 0, 0, 0);
}

// ---------------------------------------------------------------------------
// Phase A (MFMA): UT[v][k] = sum_j VT[v][j] * (w_j * KT[k][j]),  w_j=exp(cumC-cum_j)
// ---------------------------------------------------------------------------
__global__ void __launch_bounds__(256) gla_phaseA(const u16* __restrict__ KT, const u16* __restrict__ VT,
                                                  const float* __restrict__ LOGF,
                                                  float* __restrict__ U, float* __restrict__ DC) {
  const int blk = blockIdx.x;
  const int bh = blk >> 5, c = blk & 31;
  const int tid = threadIdx.x;
  const int wave = tid >> 6, lane = tid & 63;
  const int wr = wave >> 1, wc = wave & 1, l15 = lane & 15, q8 = (lane >> 4) * 8;
  __shared__ u16 SA[128 * 40];
  __shared__ u16 SB[128 * 40];
  __shared__ float cum[CHUNK_];
  __shared__ float wd[CHUNK_];
  scan_chunk(LOGF + (size_t)bh * N_ + c * CHUNK_, cum, tid);
  if (tid < 128) wd[tid] = expf(cum[127] - cum[tid]);
  __syncthreads();
  const u16* vbase = VT + ((size_t)bh * R_) * N_ + (size_t)c * CHUNK_;
  const u16* kbase = KT + ((size_t)bh * R_) * N_ + (size_t)c * CHUNK_;
  f32x4 acc[4][4];
#pragma unroll
  for (int i = 0; i < 4; i++)
#pragma unroll
    for (int j = 0; j < 4; j++) acc[i][j] = (f32x4){0.f, 0.f, 0.f, 0.f};
  for (int j0 = 0; j0 < CHUNK_; j0 += 32) {
    __syncthreads();
    stage32(SA, vbase + j0, N_, tid);
    stage32_scaled(SB, kbase + j0, N_, wd, j0, tid);
    __syncthreads();
    mfma16(acc, SA, SB, wr, wc, l15, q8);
  }
  float* Up = U + (size_t)blk * (R_ * R_);
#pragma unroll
  for (int mi = 0; mi < 4; mi++) {
#pragma unroll
    for (int ni = 0; ni < 4; ni++) {
      int v = wr * 64 + mi * 16 + (lane >> 4) * 4;
      int k = wc * 64 + ni * 16 + l15;
#pragma unroll
      for (int r = 0; r < 4; r++) Up[(size_t)(v + r) * R_ + k] = acc[mi][ni][r];
    }
  }
  if (tid == 0) DC[blk] = expf(cum[127]);
}

// ---------------------------------------------------------------------------
// Phase B: propagate chunk-start states; U fp32 [v][k] -> SS bf16 [v][k]
// ---------------------------------------------------------------------------
__global__ void __launch_bounds__(256) gla_phaseB(const float* __restrict__ U, const float* __restrict__ DC,
                                                  u16* __restrict__ SSb) {
  int idx = blockIdx.x * 256 + threadIdx.x;
  int bh = idx >> 14;
  int e = idx & 16383;
  float s = 0.f;
  for (int c = 0; c < NC_; c++) {
    size_t off = ((size_t)bh * NC_ + c) * 16384 + e;
    SSb[off] = f2b(s);
    s = DC[bh * NC_ + c] * s + U[off];
  }
}

// ---------------------------------------------------------------------------
// Phase C (MFMA): o_i = exp(cum_i)*q_i@Sstart + sum_{j<=i} exp(cum_i-cum_j)(q_i.k_j) v_j
// ---------------------------------------------------------------------------
__global__ void __launch_bounds__(256) gla_phaseC(const u16* __restrict__ Qb, const u16* __restrict__ Kb,
                                                  const u16* __restrict__ VT, const u16* __restrict__ SSb,
                                                  const float* __restrict__ LOGF, u16* __restrict__ Ob) {
  const int blk = blockIdx.x;
  const int bh = blk >> 5, c = blk & 31;
  const int b = bh >> 3, h = bh & 7;
  const int tid = threadIdx.x;
  const int wave = tid >> 6, lane = tid & 63;
  const int wr = wave >> 1, wc = wave & 1, l15 = lane & 15;
  const int q4i = (lane >> 4) * 4, q8 = (lane >> 4) * 8;
  __shared__ u16 SA[128 * 40];
  __shared__ u16 SB[128 * 40];
  __shared__ u16 Ps[128 * 136];
  __shared__ float cum[CHUNK_];
  __shared__ float cumE[CHUNK_];
  scan_chunk(LOGF + (size_t)bh * N_ + c * CHUNK_, cum, tid);
  if (tid < 128) cumE[tid] = expf(cum[tid]);
  __syncthreads();
  const size_t rowbase = ((size_t)(b * N_ + c * CHUNK_)) * E_ + (size_t)h * R_;
  const u16* vtbase = VT + ((size_t)bh * R_) * N_ + (size_t)c * CHUNK_;
  const u16* ssbase = SSb + (size_t)blk * (R_ * R_);

  f32x4 acc[4][4];
#pragma unroll
  for (int i = 0; i < 4; i++)
#pragma unroll
    for (int j = 0; j < 4; j++) acc[i][j] = (f32x4){0.f, 0.f, 0.f, 0.f};

  // ---- S^T = K @ Q^T ----
  for (int r0 = 0; r0 < R_; r0 += 32) {
    __syncthreads();
    stage32(SA, Kb + rowbase + r0, E_, tid);   // rows j
    stage32(SB, Qb + rowbase + r0, E_, tid);   // rows i
    __syncthreads();
    mfma16(acc, SA, SB, wr, wc, l15, q8);
  }
  // ---- mask + decay -> Ps[i][j] ----
#pragma unroll
  for (int mi = 0; mi < 4; mi++) {
#pragma unroll
    for (int ni = 0; ni < 4; ni++) {
      int jb = wr * 64 + mi * 16 + q4i;
      int i = wc * 64 + ni * 16 + l15;
      float ci = cum[i];
      float4 cj = *(const float4*)&cum[jb];
      u16x4 pk;
      float cjv[4] = {cj.x, cj.y, cj.z, cj.w};
#pragma unroll
      for (int r = 0; r < 4; r++) {
        int j = jb + r;
        float w = (j <= i) ? expf(ci - cjv[r]) : 0.f;
        pk[r] = f2b(acc[mi][ni][r] * w);
      }
      *(u16x4*)&Ps[i * 136 + jb] = pk;
    }
  }
  // ---- term1: Q @ SS^T ----
#pragma unroll
  for (int i = 0; i < 4; i++)
#pragma unroll
    for (int j = 0; j < 4; j++) acc[i][j] = (f32x4){0.f, 0.f, 0.f, 0.f};
  for (int k0 = 0; k0 < R_; k0 += 32) {
    __syncthreads();
    stage32(SA, Qb + rowbase + k0, E_, tid);     // rows i
    stage32(SB, ssbase + k0, R_, tid);           // rows v (SS^T layout [v][k])
    __syncthreads();
    mfma16(acc, SA, SB, wr, wc, l15, q8);
  }
#pragma unroll
  for (int mi = 0; mi < 4; mi++) {
    float4 e4 = *(const float4*)&cumE[wr * 64 + mi * 16 + q4i];
    float ev[4] = {e4.x, e4.y, e4.z, e4.w};
#pragma unroll
    for (int ni = 0; ni < 4; ni++)
#pragma unroll
      for (int r = 0; r < 4; r++) acc[mi][ni][r] *= ev[r];
  }
  // ---- term2: acc += P @ V^T ----
  for (int j0 = 0; j0 < CHUNK_; j0 += 32) {
    __syncthreads();
    stage32(SB, vtbase + j0, N_, tid);           // rows v
    __syncthreads();
    if (wr == 1 || j0 < 64) {                    // wr==0 waves: j>=64 all masked
      bf16x8 af[4], bf[4];
#pragma unroll
      for (int mi = 0; mi < 4; mi++)
        af[mi] = *(const bf16x8*)&Ps[(wr * 64 + mi * 16 + l15) * 136 + j0 + q8];
#pragma unroll
      for (int ni = 0; ni < 4; ni++)
        bf[ni] = *(const bf16x8*)&SB[(wc * 64 + ni * 16 + l15) * 40 + q8];
#pragma unroll
      for (int mi = 0; mi < 4; mi++)
#pragma unroll
        for (int ni = 0; ni < 4; ni++)
          acc[mi][ni] = __builtin_amdgcn_mfma_f32_16x16x32_bf16(af[mi], bf[ni], acc[mi][ni], 0, 0, 0);
    }
  }
  // ---- write O (bf16, row-major [m][E]) ----
#pragma unroll
  for (int mi = 0; mi < 4; mi++) {
#pragma unroll
    for (int ni = 0; ni < 4; ni++) {
      int i = wr * 64 + mi * 16 + q4i;
      int v = wc * 64 + ni * 16 + l15;
#pragma unroll
      for (int r = 0; r < 4; r++)
        Ob[rowbase + (size_t)(i + r) * E_ + v] = f2b(acc[mi][ni][r]);
    }
  }
}

// ---------------------------------------------------------------------------
// o = o * gate (both bf16); LayerNorm(weight-only, fp32 gamma) -> bf16
// ---------------------------------------------------------------------------
__global__ void __launch_bounds__(256) gate_ln(const u16* __restrict__ O, const u16* __restrict__ G,
                                               const float* __restrict__ gamma, u16* __restrict__ OLN) {
  int row = blockIdx.x, tid = threadIdx.x;
  u16x4 o4 = *(const u16x4*)(O + (size_t)row * E_ + tid * 4);
  u16x4 g4 = *(const u16x4*)(G + (size_t)row * E_ + tid * 4);
  float x0 = b2f(o4[0]) * b2f(g4[0]), x1 = b2f(o4[1]) * b2f(g4[1]);
  float x2 = b2f(o4[2]) * b2f(g4[2]), x3 = b2f(o4[3]) * b2f(g4[3]);
  float s = x0 + x1 + x2 + x3;
  float sq = x0 * x0 + x1 * x1 + x2 * x2 + x3 * x3;
  __shared__ float red[8];
#pragma unroll
  for (int m = 1; m < 64; m <<= 1) { s += __shfl_xor(s, m); sq += __shfl_xor(sq, m); }
  int wid = tid >> 6;
  if ((tid & 63) == 0) { red[wid] = s; red[4 + wid] = sq; }
  __syncthreads();
  s = red[0] + red[1] + red[2] + red[3];
  sq = red[4] + red[5] + red[6] + red[7];
  float mu = s * (1.f / 1024.f);
  float var = sq * (1.f / 1024.f) - mu * mu;
  float rs = rsqrtf(var + 1e-5f);
  int e = tid * 4;
  u16x4 r4;
  r4[0] = f2b((x0 - mu) * rs * gamma[e + 0]);
  r4[1] = f2b((x1 - mu) * rs * gamma[e + 1]);
  r4[2] = f2b((x2 - mu) * rs * gamma[e + 2]);
  r4[3] = f2b((x3 - mu) * rs * gamma[e + 3]);
  *(u16x4*)(OLN + (size_t)row * E_ + e) = r4;
}

// ---------------------------------------------------------------------------
extern "C" void kernel_launch(void* const* d_in, const int* in_sizes, int n_in,
                              void* d_out, int out_size, void* d_ws, size_t ws_size,
                              hipStream_t stream) {
  (void)in_sizes; (void)n_in; (void)out_size; (void)ws_size;
  const float* x   = (const float*)d_in[0];
  const float* llb = (const float*)d_in[1];
  const float* Wq  = (const float*)d_in[2];
  const float* Wk  = (const float*)d_in[3];
  const float* Wv  = (const float*)d_in[4];
  const float* Wf  = (const float*)d_in[5];
  const float* Wb1 = (const float*)d_in[6];
  const float* Wb2 = (const float*)d_in[7];
  const float* Wg1 = (const float*)d_in[8];
  const float* Wg2 = (const float*)d_in[9];
  const float* gm  = (const float*)d_in[10];
  const float* Wo  = (const float*)d_in[11];
  float* out = (float*)d_out;

  char* ws = (char*)d_ws;
  const size_t SZB = (size_t)M_ * E_ * 2;            // 16.78 MB bf16 [M,E]
  u16*   Qb    = (u16*)(ws + 0 * SZB);               // q bf16 (OLN overlays later)
  u16*   Kb    = (u16*)(ws + 1 * SZB);
  u16*   KT    = (u16*)(ws + 2 * SZB);               // [B,H,R,N]
  u16*   VT    = (u16*)(ws + 3 * SZB);               // [B,H,R,N]
  u16*   BETAb = (u16*)(ws + 4 * SZB);               // beta -> O overlay
  u16*   GATEb = (u16*)(ws + 5 * SZB);
  u16*   SSb   = (u16*)(ws + 6 * SZB);               // chunk-start states bf16 [v][k]
  u16*   XB    = (u16*)(ws + 7 * SZB);
  float* U     = (float*)(ws + 8 * SZB);             // fp32 [512][128][128]
  char*  tail  = ws + 8 * SZB + (size_t)BH_ * NC_ * R_ * R_ * 4;
  u16*   Wcat  = (u16*)tail;                         // [3456][1024]
  u16*   Wcat2 = Wcat + (size_t)3456 * 1024;         // [2048][256]
  u16*   WOb   = Wcat2 + (size_t)2048 * 256;         // [1024][1024]
  u16*   T1    = WOb + (size_t)E_ * E_;              // [M,256]
  float* LOGF  = (float*)(T1 + (size_t)M_ * 256);
  float* DC    = LOGF + (size_t)BH_ * N_;
  u16*   Ob    = BETAb;                              // overlay (beta dead after householder)
  u16*   OLN   = Qb;                                 // overlay (q dead after phaseC)

  CvtArgs ca;
  ca.src[0] = x;   ca.dst[0]  = XB;
  ca.src[1] = Wq;  ca.dst[1]  = Wcat;
  ca.src[2] = Wk;  ca.dst[2]  = Wcat + (size_t)1024 * 1024;
  ca.src[3] = Wv;  ca.dst[3]  = Wcat + (size_t)2048 * 1024;
  ca.src[4] = Wf;  ca.dst[4]  = Wcat + (size_t)3328 * 1024;
  ca.src[5] = Wb1; ca.dst[5]  = Wcat + (size_t)3072 * 1024;
  ca.src[6] = Wb2; ca.dst[6]  = Wcat2;
  ca.src[7] = Wg1; ca.dst[7]  = Wcat + (size_t)3200 * 1024;
  ca.src[8] = Wg2; ca.dst[8]  = Wcat2;
  ca.src[9] = Wo;  ca.dst[9]  = WOb;
  ca.dst[10] = Wcat + (size_t)3336 * 1024;           // zero pad rows

  dim3 blk(256);
  cvt_all<<<dim3(12928), blk, 0, stream>>>(ca);
  mega_gemm<<<dim3(64, 27), blk, 0, stream>>>(XB, Wcat, llb, Qb, Kb, KT, VT, T1, LOGF);
  bg_gemm<<<dim3(64, 16), blk, 0, stream>>>(T1, Wcat2, BETAb, GATEb);
  householder<<<dim3(M_), blk, 0, stream>>>(Qb, BETAb);
  gla_phaseA<<<dim3(BH_ * NC_), blk, 0, stream>>>(KT, VT, LOGF, U, DC);
  gla_phaseB<<<dim3(BH_ * 16384 / 256), blk, 0, stream>>>(U, DC, SSb);
  gla_phaseC<<<dim3(BH_ * NC_), blk, 0, stream>>>(Qb, Kb, VT, SSb, LOGF, Ob);
  gate_ln<<<dim3(M_), blk, 0, stream>>>(Ob, GATEb, gm, OLN);
  out_gemm<<<dim3(64, 8), blk, 0, stream>>>(OLN, WOb, out);
}

// Round 5
// 317.846 us; speedup vs baseline: 1.6128x; 1.0808x over previous
//
#include <hip/hip_runtime.h>
#include <hip/hip_bf16.h>

using u16 = unsigned short;
typedef __attribute__((ext_vector_type(8))) short bf16x8;
typedef __attribute__((ext_vector_type(4))) float f32x4;
typedef __attribute__((ext_vector_type(8))) u16 u16x8;
typedef __attribute__((ext_vector_type(4))) u16 u16x4;

#define B_ 2
#define N_ 4096
#define E_ 1024
#define R_ 128
#define H_ 8
#define M_ 8192      // B*N
#define CHUNK_ 128
#define NC_ 32       // N/CHUNK
#define BH_ 16       // B*H

__device__ __forceinline__ float b2f(u16 u) { return __uint_as_float(((unsigned)u) << 16); }
__device__ __forceinline__ u16 f2b(float f) {
  unsigned u = __float_as_uint(f);
  return (u16)((u + 0x7fffu + ((u >> 16) & 1u)) >> 16);   // RNE
}
// fast sigmoid / silu (native v_exp + v_rcp; rel err ~2^-21, fine for bf16 out)
__device__ __forceinline__ float sigm(float x) {
  return __builtin_amdgcn_rcpf(1.0f + __expf(-x));
}

#define GLDS(g, l) __builtin_amdgcn_global_load_lds( \
    (const __attribute__((address_space(1))) unsigned int*)(g), \
    (__attribute__((address_space(3))) unsigned int*)(l), 16, 0, 0)

// ---------------------------------------------------------------------------
// fp32 -> bf16 conversion. Segments: x, Wq,Wk,Wv (into Wcat), Wf(into Wcat),
// Wb1,Wg1(into Wcat), Wb2/Wg2 (block-diagonal into Wcat2 + zero halves),
// Wo, and zero-fill of Wcat pad rows 3336-3455.
// ---------------------------------------------------------------------------
struct CvtArgs {
  const float* src[10];
  u16* dst[11];
};

__global__ void __launch_bounds__(256) cvt_all(CvtArgs a) {
  int idx = blockIdx.x * 256 + threadIdx.x;   // float4-granule index; grid exact
  const int SZ[11] = {2097152, 262144, 262144, 262144, 2048,
                      32768, 32768, 32768, 32768, 262144, 30720};
  int off = idx, seg = 0;
#pragma unroll
  for (int i = 0; i < 10; i++) {
    if (seg == i && off >= SZ[i]) { off -= SZ[i]; seg = i + 1; }
  }
  u16x4 z = (u16x4){0, 0, 0, 0};
  if (seg == 10) { ((u16x4*)a.dst[10])[off] = z; return; }   // Wcat pad rows
  float4 v = ((const float4*)a.src[seg])[off];
  u16x4 r;
  r[0] = f2b(v.x); r[1] = f2b(v.y); r[2] = f2b(v.z); r[3] = f2b(v.w);
  if (seg == 6) {              // Wb2 -> Wcat2 rows 0-1023, cols 0-127 (+zero cols 128-255)
    int n = off >> 5, c = off & 31;
    u16x4* W2 = (u16x4*)a.dst[6];
    W2[n * 64 + c] = r; W2[n * 64 + 32 + c] = z;
  } else if (seg == 8) {       // Wg2 -> Wcat2 rows 1024-2047, cols 128-255 (+zero cols 0-127)
    int n = off >> 5, c = off & 31;
    u16x4* W2 = (u16x4*)a.dst[8];
    W2[(1024 + n) * 64 + 32 + c] = r; W2[(1024 + n) * 64 + c] = z;
  } else {
    ((u16x4*)a.dst[seg])[off] = r;
  }
}

// ---------------------------------------------------------------------------
// Shared BK=64 GEMM K-loop: 128x128 block tile, two 32-wide panels per
// barrier pair (32 MFMA/barrier), global_load_lds width-16 staging.
// As/Bs: u16[8192] each (two [128][32] panels).
// ---------------------------------------------------------------------------
__device__ __forceinline__ void mfma_panel(f32x4 (&acc)[4][4], const u16* A, const u16* Bm,
                                           int wr, int wc, int l15, int q8) {
  bf16x8 af[4], bf[4];
#pragma unroll
  for (int mi = 0; mi < 4; mi++) af[mi] = *(const bf16x8*)&A[(wr * 64 + mi * 16 + l15) * 32 + q8];
#pragma unroll
  for (int ni = 0; ni < 4; ni++) bf[ni] = *(const bf16x8*)&Bm[(wc * 64 + ni * 16 + l15) * 32 + q8];
#pragma unroll
  for (int mi = 0; mi < 4; mi++)
#pragma unroll
    for (int ni = 0; ni < 4; ni++)
      acc[mi][ni] = __builtin_amdgcn_mfma_f32_16x16x32_bf16(af[mi], bf[ni], acc[mi][ni], 0, 0, 0);
}

__device__ __forceinline__ void gemm_loop(const u16* __restrict__ X, const u16* __restrict__ W,
                                          int m0, int n0, int K,
                                          u16* As, u16* Bs, f32x4 (&acc)[4][4], int tid) {
  const int wave = tid >> 6, lane = tid & 63;
  const int wr = wave >> 1, wc = wave & 1, l15 = lane & 15, q8 = (lane >> 4) * 8;
  const u16* Ap = X + (size_t)(m0 + wave * 32 + (lane >> 2)) * K + (lane & 3) * 8;
  const u16* Bp = W + (size_t)(n0 + wave * 32 + (lane >> 2)) * K + (lane & 3) * 8;
  u16* A0 = As + wave * 1024;
  u16* B0 = Bs + wave * 1024;
  for (int k0 = 0; k0 < K; k0 += 64) {
    GLDS(Ap + k0,                    A0);
    GLDS(Ap + 16 * (size_t)K + k0,   A0 + 512);
    GLDS(Ap + k0 + 32,               A0 + 4096);
    GLDS(Ap + 16 * (size_t)K + k0 + 32, A0 + 4608);
    GLDS(Bp + k0,                    B0);
    GLDS(Bp + 16 * (size_t)K + k0,   B0 + 512);
    GLDS(Bp + k0 + 32,               B0 + 4096);
    GLDS(Bp + 16 * (size_t)K + k0 + 32, B0 + 4608);
    __syncthreads();
    mfma_panel(acc, As, Bs, wr, wc, l15, q8);
    mfma_panel(acc, As + 4096, Bs + 4096, wr, wc, l15, q8);
    __syncthreads();
  }
}

// ---------------------------------------------------------------------------
// Mega-GEMM: X[M,1024] @ Wcat[3456,1024]^T. Per-block-column epilogue:
//  ny 0-7   : silu -> Qb
//  ny 8-15  : silu -> Kb + coalesced transposed KT[b,h,r,n] (via LDS transpose)
//  ny 16-23 : -> transposed VT only (via LDS transpose)
//  ny 24-25 : -> T1[M,256]
//  ny 26    : cols 3328-3335 = f logits -> LOGF = log(lb + (1-lb)*sigmoid(f))
// LDS: staging (As|Bs = 32 KB) overlaid by transpose buffer Ts[128][132].
// ---------------------------------------------------------------------------
__global__ void __launch_bounds__(256) mega_gemm(const u16* __restrict__ X, const u16* __restrict__ Wcat,
                                                 const float* __restrict__ llb,
                                                 u16* __restrict__ Qb, u16* __restrict__ Kb,
                                                 u16* __restrict__ KT, u16* __restrict__ VT,
                                                 u16* __restrict__ T1, float* __restrict__ LOGF) {
  __shared__ u16 sh[16896];           // As=sh, Bs=sh+8192; Ts overlays all of sh
  u16* As = sh;
  u16* Bs = sh + 8192;
  u16* Ts = sh;                       // [col][row] stride 132
  const int tid = threadIdx.x;
  const int m0 = blockIdx.x * 128;
  const int ny = blockIdx.y, n0 = ny * 128;
  f32x4 acc[4][4];
#pragma unroll
  for (int i = 0; i < 4; i++)
#pragma unroll
    for (int j = 0; j < 4; j++) acc[i][j] = (f32x4){0.f, 0.f, 0.f, 0.f};
  gemm_loop(X, Wcat, m0, n0, 1024, As, Bs, acc, tid);

  const int wave = tid >> 6, lane = tid & 63;
  const int wr = wave >> 1, wc = wave & 1, l15 = lane & 15, q4 = (lane >> 4) * 4;

  if (ny == 26) {                     // decay logits -> LOGF
#pragma unroll
    for (int mi = 0; mi < 4; mi++) {
      if (wc == 0 && l15 < 8) {
        int rbase = m0 + wr * 64 + mi * 16 + q4;
        int h = l15, bb = rbase >> 12, n = rbase & (N_ - 1);
        float lb = __expf(llb[h]);
        float4 o;
        o.x = __logf(lb + (1.f - lb) * sigm(acc[mi][0][0]));
        o.y = __logf(lb + (1.f - lb) * sigm(acc[mi][0][1]));
        o.z = __logf(lb + (1.f - lb) * sigm(acc[mi][0][2]));
        o.w = __logf(lb + (1.f - lb) * sigm(acc[mi][0][3]));
        *(float4*)&LOGF[(size_t)(bb * H_ + h) * N_ + n] = o;
      }
    }
    return;
  }

  // activation + bf16 pack
  u16 pk[4][4][4];
#pragma unroll
  for (int mi = 0; mi < 4; mi++)
#pragma unroll
    for (int ni = 0; ni < 4; ni++)
#pragma unroll
      for (int r = 0; r < 4; r++) {
        float v = acc[mi][ni][r];
        if (ny < 16) v = v * sigm(v);
        pk[mi][ni][r] = f2b(v);
      }

  // row-major stores (Qb / Kb / T1)
  if (ny < 8) {
#pragma unroll
    for (int mi = 0; mi < 4; mi++)
#pragma unroll
      for (int ni = 0; ni < 4; ni++) {
        int col = n0 + wc * 64 + ni * 16 + l15;
        int rbase = m0 + wr * 64 + mi * 16 + q4;
#pragma unroll
        for (int r = 0; r < 4; r++) Qb[(size_t)(rbase + r) * E_ + col] = pk[mi][ni][r];
      }
  } else if (ny < 16) {
#pragma unroll
    for (int mi = 0; mi < 4; mi++)
#pragma unroll
      for (int ni = 0; ni < 4; ni++) {
        int col = n0 - 1024 + wc * 64 + ni * 16 + l15;
        int rbase = m0 + wr * 64 + mi * 16 + q4;
#pragma unroll
        for (int r = 0; r < 4; r++) Kb[(size_t)(rbase + r) * E_ + col] = pk[mi][ni][r];
      }
  } else if (ny >= 24) {
#pragma unroll
    for (int mi = 0; mi < 4; mi++)
#pragma unroll
      for (int ni = 0; ni < 4; ni++) {
        int ct = n0 - 3072 + wc * 64 + ni * 16 + l15;
        int rbase = m0 + wr * 64 + mi * 16 + q4;
#pragma unroll
        for (int r = 0; r < 4; r++) T1[(size_t)(rbase + r) * 256 + ct] = pk[mi][ni][r];
      }
    return;
  }

  // transposed stores for KT (ny 8-15) / VT (ny 16-23) via LDS transpose
  if (ny < 24) {
    // write tile into Ts[col][row] (b64 per (mi,ni))
#pragma unroll
    for (int mi = 0; mi < 4; mi++)
#pragma unroll
      for (int ni = 0; ni < 4; ni++) {
        int cl = wc * 64 + ni * 16 + l15;
        int rl = wr * 64 + mi * 16 + q4;
        u16x4 w4 = {pk[mi][ni][0], pk[mi][ni][1], pk[mi][ni][2], pk[mi][ni][3]};
        *(u16x4*)&Ts[cl * 132 + rl] = w4;
      }
    __syncthreads();
    u16* TB = (ny < 16) ? KT : VT;
    int cbase = n0 - ((ny < 16) ? 1024 : 2048);     // multiple of 128
    int head = cbase >> 7;
    int bb = m0 >> 12, nloc = m0 & (N_ - 1);
    size_t base = ((size_t)(bb * H_ + head) * R_) * N_ + nloc;
#pragma unroll
    for (int p = 0; p < 8; p++) {
      int cl = p * 16 + (tid >> 4);                 // r-local 0..127
      int r8 = (tid & 15) * 8;                      // n-local chunk
      u16x8 v = *(const u16x8*)&Ts[cl * 132 + r8];
      *(u16x8*)&TB[base + (size_t)cl * N_ + r8] = v;
    }
  }
}

// ---------------------------------------------------------------------------
// beta+gate GEMM: T1[M,256] @ Wcat2[2048,256]^T (block-diagonal).
// cols 0-1023 -> silu -> BETA; cols 1024-2047 -> sigmoid -> GATE.
// ---------------------------------------------------------------------------
__global__ void __launch_bounds__(256) bg_gemm(const u16* __restrict__ T1, const u16* __restrict__ W2,
                                               u16* __restrict__ BETA, u16* __restrict__ GATE) {
  __shared__ u16 As[8192];
  __shared__ u16 Bs[8192];
  const int tid = threadIdx.x;
  const int m0 = blockIdx.x * 128;
  const int n0 = blockIdx.y * 128;
  f32x4 acc[4][4];
#pragma unroll
  for (int i = 0; i < 4; i++)
#pragma unroll
    for (int j = 0; j < 4; j++) acc[i][j] = (f32x4){0.f, 0.f, 0.f, 0.f};
  gemm_loop(T1, W2, m0, n0, 256, As, Bs, acc, tid);
  const int wave = tid >> 6, lane = tid & 63;
  const int wr = wave >> 1, wc = wave & 1, l15 = lane & 15, q4 = (lane >> 4) * 4;
#pragma unroll
  for (int mi = 0; mi < 4; mi++) {
#pragma unroll
    for (int ni = 0; ni < 4; ni++) {
      int col = n0 + wc * 64 + ni * 16 + l15;
      int rbase = m0 + wr * 64 + mi * 16 + q4;
      if (col < 1024) {
#pragma unroll
        for (int r = 0; r < 4; r++) {
          float v = acc[mi][ni][r];
          BETA[(size_t)(rbase + r) * E_ + col] = f2b(v * sigm(v));
        }
      } else {
#pragma unroll
        for (int r = 0; r < 4; r++)
          GATE[(size_t)(rbase + r) * E_ + col - 1024] = f2b(sigm(acc[mi][ni][r]));
      }
    }
  }
}

// ---------------------------------------------------------------------------
// Output GEMM: OLN[M,1024] @ Wo[1024,1024]^T -> fp32 out.
// ---------------------------------------------------------------------------
__global__ void __launch_bounds__(256) out_gemm(const u16* __restrict__ X, const u16* __restrict__ W,
                                                float* __restrict__ C) {
  __shared__ u16 As[8192];
  __shared__ u16 Bs[8192];
  const int tid = threadIdx.x;
  const int m0 = blockIdx.x * 128;
  const int n0 = blockIdx.y * 128;
  f32x4 acc[4][4];
#pragma unroll
  for (int i = 0; i < 4; i++)
#pragma unroll
    for (int j = 0; j < 4; j++) acc[i][j] = (f32x4){0.f, 0.f, 0.f, 0.f};
  gemm_loop(X, W, m0, n0, 1024, As, Bs, acc, tid);
  const int wave = tid >> 6, lane = tid & 63;
  const int wr = wave >> 1, wc = wave & 1, l15 = lane & 15, q4 = (lane >> 4) * 4;
#pragma unroll
  for (int mi = 0; mi < 4; mi++) {
#pragma unroll
    for (int ni = 0; ni < 4; ni++) {
      int col = n0 + wc * 64 + ni * 16 + l15;
      int rbase = m0 + wr * 64 + mi * 16 + q4;
#pragma unroll
      for (int r = 0; r < 4; r++)
        C[(size_t)(rbase + r) * E_ + col] = acc[mi][ni][r];
    }
  }
}

// ---------------------------------------------------------------------------
// Householder on bf16 q (in place)
// ---------------------------------------------------------------------------
__global__ void __launch_bounds__(256) householder(u16* __restrict__ Q, const u16* __restrict__ BETA) {
  int row = blockIdx.x;
  int tid = threadIdx.x;
  u16* q = Q + (size_t)row * E_;
  const u16* bt = BETA + (size_t)row * E_;
  u16x4 q4 = *(const u16x4*)(q + tid * 4);
  u16x4 b4 = *(const u16x4*)(bt + tid * 4);
  float qv[4], bv[4];
#pragma unroll
  for (int i = 0; i < 4; i++) { qv[i] = b2f(q4[i]); bv[i] = b2f(b4[i]); }
  float ss = bv[0]*bv[0] + bv[1]*bv[1] + bv[2]*bv[2] + bv[3]*bv[3];
  float qd = qv[0]*bv[0] + qv[1]*bv[1] + qv[2]*bv[2] + qv[3]*bv[3];
  __shared__ float red[8];
#pragma unroll
  for (int m = 1; m < 64; m <<= 1) { ss += __shfl_xor(ss, m); qd += __shfl_xor(qd, m); }
  int wid = tid >> 6;
  if ((tid & 63) == 0) { red[wid] = ss; red[4 + wid] = qd; }
  __syncthreads();
  ss = red[0] + red[1] + red[2] + red[3];
  qd = red[4] + red[5] + red[6] + red[7];
  float coef = 2.f * qd / (ss + 1e-12f);
  const float scale = 0.08838834764831845f;  // 128^-0.5 folded in
  u16x4 o4;
#pragma unroll
  for (int i = 0; i < 4; i++) o4[i] = f2b((qv[i] - coef * bv[i]) * scale);
  *(u16x4*)(q + tid * 4) = o4;
}

// inclusive scan of the 128 log-decay values of one chunk into cum[] (wave 0)
__device__ __forceinline__ void scan_chunk(const float* __restrict__ lf, float* cum, int tid) {
  if (tid < 64) {
    float a = lf[tid], b = lf[tid + 64];
#pragma unroll
    for (int off = 1; off < 64; off <<= 1) {
      float t = __shfl_up(a, off);  if (tid >= off) a += t;
      float t2 = __shfl_up(b, off); if (tid >= off) b += t2;
    }
    b += __shfl(a, 63);
    cum[tid] = a; cum[tid + 64] = b;
  }
  __syncthreads();
}

// stage a [128 x 32] bf16 slab (row stride `stride` elements) into LDS [128][40]
__device__ __forceinline__ void stage32(u16* dst, const u16* src, size_t stride, int tid) {
  int r0 = tid >> 2, c8 = (tid & 3) * 8;
  *(u16x8*)&dst[(size_t)r0 * 40 + c8] = *(const u16x8*)&src[(size_t)r0 * stride + c8];
  int r1 = r0 + 64;
  *(u16x8*)&dst[(size_t)r1 * 40 + c8] = *(const u16x8*)&src[(size_t)r1 * stride + c8];
}

// same, scaling column j (slab-local) by w[j0 + j]
__device__ __forceinline__ void stage32_scaled(u16* dst, const u16* src, size_t stride,
                                               const float* w, int j0, int tid) {
  int c8 = (tid & 3) * 8;
  float wv[8];
#pragma unroll
  for (int i = 0; i < 8; i++) wv[i] = w[j0 + c8 + i];
#pragma unroll
  for (int rr = 0; rr < 128; rr += 64) {
    int r = rr + (tid >> 2);
    u16x8 raw = *(const u16x8*)&src[(size_t)r * stride + c8];
    u16x8 o;
#pragma unroll
    for (int i = 0; i < 8; i++) o[i] = f2b(b2f(raw[i]) * wv[i]);
    *(u16x8*)&dst[(size_t)r * 40 + c8] = o;
  }
}

// one K=32 MFMA step over a 128x128 output (4 waves), A/B slabs in LDS [128][40]
__device__ __forceinline__ void mfma16(f32x4 (&acc)[4][4], const u16* A, const u16* Bm,
                                       int wr, int wc, int l15, int q8) {
  bf16x8 af[4], bf[4];
#pragma unroll
  for (int mi = 0; mi < 4; mi++) af[mi] = *(const bf16x8*)&A[(wr * 64 + mi * 16 + l15) * 40 + q8];
#pragma unroll
  for (int ni = 0; ni < 4; ni++) bf[ni] = *(const bf16x8*)&Bm[(wc * 64 + ni * 16 + l15) * 40 + q8];
#pragma unroll
  for (int mi = 0; mi < 4; mi++)
#pragma unroll
    for (int ni = 0; ni < 4; ni++)
      acc[mi][ni] = __builtin_amdgcn_mfma_f32_16x16x32_bf16(af[mi], bf[ni], acc[mi][ni], 0, 0, 0);
}

// ---------------------------------------------------------------------------
// Phase A (MFMA): UT[v][k] = sum_j VT[v][j] * (w_j * KT[k][j]),  w_j=exp(cumC-cum_j)
// ---------------------------------------------------------------------------
__global__ void __launch_bounds__(256) gla_phaseA(const u16* __restrict__ KT, const u16* __restrict__ VT,
                                                  const float* __restrict__ LOGF,
                                                  float* __restrict__ U, float* __restrict__ DC) {
  const int blk = blockIdx.x;
  const int bh = blk >> 5, c = blk & 31;
  const int tid = threadIdx.x;
  const int wave = tid >> 6, lane = tid & 63;
  const int wr = wave >> 1, wc = wave & 1, l15 = lane & 15, q8 = (lane >> 4) * 8;
  __shared__ u16 SA[128 * 40];
  __shared__ u16 SB[128 * 40];
  __shared__ float cum[CHUNK_];
  __shared__ float wd[CHUNK_];
  scan_chunk(LOGF + (size_t)bh * N_ + c * CHUNK_, cum, tid);
  if (tid < 128) wd[tid] = __expf(cum[127] - cum[tid]);
  __syncthreads();
  const u16* vbase = VT + ((size_t)bh * R_) * N_ + (size_t)c * CHUNK_;
  const u16* kbase = KT + ((size_t)bh * R_) * N_ + (size_t)c * CHUNK_;
  f32x4 acc[4][4];
#pragma unroll
  for (int i = 0; i < 4; i++)
#pragma unroll
    for (int j = 0; j < 4; j++) acc[i][j] = (f32x4){0.f, 0.f, 0.f, 0.f};
  for (int j0 = 0; j0 < CHUNK_; j0 += 32) {
    __syncthreads();
    stage32(SA, vbase + j0, N_, tid);
    stage32_scaled(SB, kbase + j0, N_, wd, j0, tid);
    __syncthreads();
    mfma16(acc, SA, SB, wr, wc, l15, q8);
  }
  float* Up = U + (size_t)blk * (R_ * R_);
#pragma unroll
  for (int mi = 0; mi < 4; mi++) {
#pragma unroll
    for (int ni = 0; ni < 4; ni++) {
      int v = wr * 64 + mi * 16 + (lane >> 4) * 4;
      int k = wc * 64 + ni * 16 + l15;
#pragma unroll
      for (int r = 0; r < 4; r++) Up[(size_t)(v + r) * R_ + k] = acc[mi][ni][r];
    }
  }
  if (tid == 0) DC[blk] = __expf(cum[127]);
}

// ---------------------------------------------------------------------------
// Phase B: propagate chunk-start states; U fp32 [v][k] -> SS bf16 [v][k]
// ---------------------------------------------------------------------------
__global__ void __launch_bounds__(256) gla_phaseB(const float* __restrict__ U, const float* __restrict__ DC,
                                                  u16* __restrict__ SSb) {
  int idx = blockIdx.x * 256 + threadIdx.x;
  int bh = idx >> 14;
  int e = idx & 16383;
  float s = 0.f;
  for (int c = 0; c < NC_; c++) {
    size_t off = ((size_t)bh * NC_ + c) * 16384 + e;
    SSb[off] = f2b(s);
    s = DC[bh * NC_ + c] * s + U[off];
  }
}

// ---------------------------------------------------------------------------
// Phase C (MFMA): o_i = exp(cum_i)*q_i@Sstart + sum_{j<=i} exp(cum_i-cum_j)(q_i.k_j) v_j
// ---------------------------------------------------------------------------
__global__ void __launch_bounds__(256) gla_phaseC(const u16* __restrict__ Qb, const u16* __restrict__ Kb,
                                                  const u16* __restrict__ VT, const u16* __restrict__ SSb,
                                                  const float* __restrict__ LOGF, u16* __restrict__ Ob) {
  const int blk = blockIdx.x;
  const int bh = blk >> 5, c = blk & 31;
  const int b = bh >> 3, h = bh & 7;
  const int tid = threadIdx.x;
  const int wave = tid >> 6, lane = tid & 63;
  const int wr = wave >> 1, wc = wave & 1, l15 = lane & 15;
  const int q4i = (lane >> 4) * 4, q8 = (lane >> 4) * 8;
  __shared__ u16 SA[128 * 40];
  __shared__ u16 SB[128 * 40];
  __shared__ u16 Ps[128 * 136];
  __shared__ float cum[CHUNK_];
  __shared__ float cumE[CHUNK_];
  scan_chunk(LOGF + (size_t)bh * N_ + c * CHUNK_, cum, tid);
  if (tid < 128) cumE[tid] = __expf(cum[tid]);
  __syncthreads();
  const size_t rowbase = ((size_t)(b * N_ + c * CHUNK_)) * E_ + (size_t)h * R_;
  const u16* vtbase = VT + ((size_t)bh * R_) * N_ + (size_t)c * CHUNK_;
  const u16* ssbase = SSb + (size_t)blk * (R_ * R_);

  f32x4 acc[4][4];
#pragma unroll
  for (int i = 0; i < 4; i++)
#pragma unroll
    for (int j = 0; j < 4; j++) acc[i][j] = (f32x4){0.f, 0.f, 0.f, 0.f};

  // ---- S^T = K @ Q^T ----
  for (int r0 = 0; r0 < R_; r0 += 32) {
    __syncthreads();
    stage32(SA, Kb + rowbase + r0, E_, tid);   // rows j
    stage32(SB, Qb + rowbase + r0, E_, tid);   // rows i
    __syncthreads();
    mfma16(acc, SA, SB, wr, wc, l15, q8);
  }
  // ---- mask + decay -> Ps[i][j] ----
#pragma unroll
  for (int mi = 0; mi < 4; mi++) {
#pragma unroll
    for (int ni = 0; ni < 4; ni++) {
      int jb = wr * 64 + mi * 16 + q4i;
      int i = wc * 64 + ni * 16 + l15;
      float ci = cum[i];
      float4 cj = *(const float4*)&cum[jb];
      u16x4 pk;
      float cjv[4] = {cj.x, cj.y, cj.z, cj.w};
#pragma unroll
      for (int r = 0; r < 4; r++) {
        int j = jb + r;
        float w = (j <= i) ? __expf(ci - cjv[r]) : 0.f;
        pk[r] = f2b(acc[mi][ni][r] * w);
      }
      *(u16x4*)&Ps[i * 136 + jb] = pk;
    }
  }
  // ---- term1: Q @ SS^T ----
#pragma unroll
  for (int i = 0; i < 4; i++)
#pragma unroll
    for (int j = 0; j < 4; j++) acc[i][j] = (f32x4){0.f, 0.f, 0.f, 0.f};
  for (int k0 = 0; k0 < R_; k0 += 32) {
    __syncthreads();
    stage32(SA, Qb + rowbase + k0, E_, tid);     // rows i
    stage32(SB, ssbase + k0, R_, tid);           // rows v (SS^T layout [v][k])
    __syncthreads();
    mfma16(acc, SA, SB, wr, wc, l15, q8);
  }
#pragma unroll
  for (int mi = 0; mi < 4; mi++) {
    float4 e4 = *(const float4*)&cumE[wr * 64 + mi * 16 + q4i];
    float ev[4] = {e4.x, e4.y, e4.z, e4.w};
#pragma unroll
    for (int ni = 0; ni < 4; ni++)
#pragma unroll
      for (int r = 0; r < 4; r++) acc[mi][ni][r] *= ev[r];
  }
  // ---- term2: acc += P @ V^T ----
  for (int j0 = 0; j0 < CHUNK_; j0 += 32) {
    __syncthreads();
    stage32(SB, vtbase + j0, N_, tid);           // rows v
    __syncthreads();
    if (wr == 1 || j0 < 64) {                    // wr==0 waves: j>=64 all masked
      bf16x8 af[4], bf[4];
#pragma unroll
      for (int mi = 0; mi < 4; mi++)
        af[mi] = *(const bf16x8*)&Ps[(wr * 64 + mi * 16 + l15) * 136 + j0 + q8];
#pragma unroll
      for (int ni = 0; ni < 4; ni++)
        bf[ni] = *(const bf16x8*)&SB[(wc * 64 + ni * 16 + l15) * 40 + q8];
#pragma unroll
      for (int mi = 0; mi < 4; mi++)
#pragma unroll
        for (int ni = 0; ni < 4; ni++)
          acc[mi][ni] = __builtin_amdgcn_mfma_f32_16x16x32_bf16(af[mi], bf[ni], acc[mi][ni], 0, 0, 0);
    }
  }
  // ---- write O (bf16, row-major [m][E]) ----
#pragma unroll
  for (int mi = 0; mi < 4; mi++) {
#pragma unroll
    for (int ni = 0; ni < 4; ni++) {
      int i = wr * 64 + mi * 16 + q4i;
      int v = wc * 64 + ni * 16 + l15;
#pragma unroll
      for (int r = 0; r < 4; r++)
        Ob[rowbase + (size_t)(i + r) * E_ + v] = f2b(acc[mi][ni][r]);
    }
  }
}

// ---------------------------------------------------------------------------
// o = o * gate (both bf16); LayerNorm(weight-only, fp32 gamma) -> bf16
// ---------------------------------------------------------------------------
__global__ void __launch_bounds__(256) gate_ln(const u16* __restrict__ O, const u16* __restrict__ G,
                                               const float* __restrict__ gamma, u16* __restrict__ OLN) {
  int row = blockIdx.x, tid = threadIdx.x;
  u16x4 o4 = *(const u16x4*)(O + (size_t)row * E_ + tid * 4);
  u16x4 g4 = *(const u16x4*)(G + (size_t)row * E_ + tid * 4);
  float x0 = b2f(o4[0]) * b2f(g4[0]), x1 = b2f(o4[1]) * b2f(g4[1]);
  float x2 = b2f(o4[2]) * b2f(g4[2]), x3 = b2f(o4[3]) * b2f(g4[3]);
  float s = x0 + x1 + x2 + x3;
  float sq = x0 * x0 + x1 * x1 + x2 * x2 + x3 * x3;
  __shared__ float red[8];
#pragma unroll
  for (int m = 1; m < 64; m <<= 1) { s += __shfl_xor(s, m); sq += __shfl_xor(sq, m); }
  int wid = tid >> 6;
  if ((tid & 63) == 0) { red[wid] = s; red[4 + wid] = sq; }
  __syncthreads();
  s = red[0] + red[1] + red[2] + red[3];
  sq = red[4] + red[5] + red[6] + red[7];
  float mu = s * (1.f / 1024.f);
  float var = sq * (1.f / 1024.f) - mu * mu;
  float rs = rsqrtf(var + 1e-5f);
  int e = tid * 4;
  u16x4 r4;
  r4[0] = f2b((x0 - mu) * rs * gamma[e + 0]);
  r4[1] = f2b((x1 - mu) * rs * gamma[e + 1]);
  r4[2] = f2b((x2 - mu) * rs * gamma[e + 2]);
  r4[3] = f2b((x3 - mu) * rs * gamma[e + 3]);
  *(u16x4*)(OLN + (size_t)row * E_ + e) = r4;
}

// ---------------------------------------------------------------------------
extern "C" void kernel_launch(void* const* d_in, const int* in_sizes, int n_in,
                              void* d_out, int out_size, void* d_ws, size_t ws_size,
                              hipStream_t stream) {
  (void)in_sizes; (void)n_in; (void)out_size; (void)ws_size;
  const float* x   = (const float*)d_in[0];
  const float* llb = (const float*)d_in[1];
  const float* Wq  = (const float*)d_in[2];
  const float* Wk  = (const float*)d_in[3];
  const float* Wv  = (const float*)d_in[4];
  const float* Wf  = (const float*)d_in[5];
  const float* Wb1 = (const float*)d_in[6];
  const float* Wb2 = (const float*)d_in[7];
  const float* Wg1 = (const float*)d_in[8];
  const float* Wg2 = (const float*)d_in[9];
  const float* gm  = (const float*)d_in[10];
  const float* Wo  = (const float*)d_in[11];
  float* out = (float*)d_out;

  char* ws = (char*)d_ws;
  const size_t SZB = (size_t)M_ * E_ * 2;            // 16.78 MB bf16 [M,E]
  u16*   Qb    = (u16*)(ws + 0 * SZB);               // q bf16 (OLN overlay later)
  u16*   Kb    = (u16*)(ws + 1 * SZB);
  u16*   KT    = (u16*)(ws + 2 * SZB);               // [B,H,R,N]
  u16*   VT    = (u16*)(ws + 3 * SZB);               // [B,H,R,N]
  u16*   BETAb = (u16*)(ws + 4 * SZB);               // beta -> O overlay
  u16*   GATEb = (u16*)(ws + 5 * SZB);
  u16*   SSb   = (u16*)(ws + 6 * SZB);               // chunk-start states bf16 [v][k]
  u16*   XB    = (u16*)(ws + 7 * SZB);
  float* U     = (float*)(ws + 8 * SZB);             // fp32 [512][128][128]
  char*  tail  = ws + 8 * SZB + (size_t)BH_ * NC_ * R_ * R_ * 4;
  u16*   Wcat  = (u16*)tail;                         // [3456][1024]
  u16*   Wcat2 = Wcat + (size_t)3456 * 1024;         // [2048][256]
  u16*   WOb   = Wcat2 + (size_t)2048 * 256;         // [1024][1024]
  u16*   T1    = WOb + (size_t)E_ * E_;              // [M,256]
  float* LOGF  = (float*)(T1 + (size_t)M_ * 256);
  float* DC    = LOGF + (size_t)BH_ * N_;
  u16*   Ob    = BETAb;                              // overlay (beta dead after householder)
  u16*   OLN   = Qb;                                 // overlay (q dead after phaseC)

  CvtArgs ca;
  ca.src[0] = x;   ca.dst[0]  = XB;
  ca.src[1] = Wq;  ca.dst[1]  = Wcat;
  ca.src[2] = Wk;  ca.dst[2]  = Wcat + (size_t)1024 * 1024;
  ca.src[3] = Wv;  ca.dst[3]  = Wcat + (size_t)2048 * 1024;
  ca.src[4] = Wf;  ca.dst[4]  = Wcat + (size_t)3328 * 1024;
  ca.src[5] = Wb1; ca.dst[5]  = Wcat + (size_t)3072 * 1024;
  ca.src[6] = Wb2; ca.dst[6]  = Wcat2;
  ca.src[7] = Wg1; ca.dst[7]  = Wcat + (size_t)3200 * 1024;
  ca.src[8] = Wg2; ca.dst[8]  = Wcat2;
  ca.src[9] = Wo;  ca.dst[9]  = WOb;
  ca.dst[10] = Wcat + (size_t)3336 * 1024;           // zero pad rows

  dim3 blk(256);
  cvt_all<<<dim3(12928), blk, 0, stream>>>(ca);
  mega_gemm<<<dim3(64, 27), blk, 0, stream>>>(XB, Wcat, llb, Qb, Kb, KT, VT, T1, LOGF);
  bg_gemm<<<dim3(64, 16), blk, 0, stream>>>(T1, Wcat2, BETAb, GATEb);
  householder<<<dim3(M_), blk, 0, stream>>>(Qb, BETAb);
  gla_phaseA<<<dim3(BH_ * NC_), blk, 0, stream>>>(KT, VT, LOGF, U, DC);
  gla_phaseB<<<dim3(BH_ * 16384 / 256), blk, 0, stream>>>(U, DC, SSb);
  gla_phaseC<<<dim3(BH_ * NC_), blk, 0, stream>>>(Qb, Kb, VT, SSb, LOGF, Ob);
  gate_ln<<<dim3(M_), blk, 0, stream>>>(Ob, GATEb, gm, OLN);
  out_gemm<<<dim3(64, 8), blk, 0, stream>>>(OLN, WOb, out);
}

// Round 7
// 316.636 us; speedup vs baseline: 1.6189x; 1.0038x over previous
//
#include <hip/hip_runtime.h>
#include <hip/hip_bf16.h>

using u16 = unsigned short;
typedef __attribute__((ext_vector_type(8))) short bf16x8;
typedef __attribute__((ext_vector_type(4))) float f32x4;
typedef __attribute__((ext_vector_type(8))) u16 u16x8;
typedef __attribute__((ext_vector_type(4))) u16 u16x4;

#define B_ 2
#define N_ 4096
#define E_ 1024
#define R_ 128
#define H_ 8
#define M_ 8192      // B*N
#define CHUNK_ 128
#define NC_ 32       // N/CHUNK
#define BH_ 16       // B*H

__device__ __forceinline__ float b2f(u16 u) { return __uint_as_float(((unsigned)u) << 16); }
__device__ __forceinline__ u16 f2b(float f) {
  unsigned u = __float_as_uint(f);
  return (u16)((u + 0x7fffu + ((u >> 16) & 1u)) >> 16);   // RNE
}
// fast sigmoid (native v_exp + v_rcp; rel err ~2^-21, fine for bf16 out)
__device__ __forceinline__ float sigm(float x) {
  return __builtin_amdgcn_rcpf(1.0f + __expf(-x));
}

#define GLDS(g, l) __builtin_amdgcn_global_load_lds( \
    (const __attribute__((address_space(1))) unsigned int*)(g), \
    (__attribute__((address_space(3))) unsigned int*)(l), 16, 0, 0)

// ---------------------------------------------------------------------------
// fp32 -> bf16 conversion (x, weights into Wcat/Wcat2/Wo, zero pad).
// ---------------------------------------------------------------------------
struct CvtArgs {
  const float* src[10];
  u16* dst[11];
};

__global__ void __launch_bounds__(256) cvt_all(CvtArgs a) {
  int idx = blockIdx.x * 256 + threadIdx.x;   // float4-granule index; grid exact
  const int SZ[11] = {2097152, 262144, 262144, 262144, 2048,
                      32768, 32768, 32768, 32768, 262144, 30720};
  int off = idx, seg = 0;
#pragma unroll
  for (int i = 0; i < 10; i++) {
    if (seg == i && off >= SZ[i]) { off -= SZ[i]; seg = i + 1; }
  }
  u16x4 z = (u16x4){0, 0, 0, 0};
  if (seg == 10) { ((u16x4*)a.dst[10])[off] = z; return; }   // Wcat pad rows
  float4 v = ((const float4*)a.src[seg])[off];
  u16x4 r;
  r[0] = f2b(v.x); r[1] = f2b(v.y); r[2] = f2b(v.z); r[3] = f2b(v.w);
  if (seg == 6) {              // Wb2 -> Wcat2 rows 0-1023, cols 0-127 (+zero cols 128-255)
    int n = off >> 5, c = off & 31;
    u16x4* W2 = (u16x4*)a.dst[6];
    W2[n * 64 + c] = r; W2[n * 64 + 32 + c] = z;
  } else if (seg == 8) {       // Wg2 -> Wcat2 rows 1024-2047, cols 128-255 (+zero cols 0-127)
    int n = off >> 5, c = off & 31;
    u16x4* W2 = (u16x4*)a.dst[8];
    W2[(1024 + n) * 64 + 32 + c] = r; W2[(1024 + n) * 64 + c] = z;
  } else {
    ((u16x4*)a.dst[seg])[off] = r;
  }
}

// ---------------------------------------------------------------------------
// BK=64 GEMM K-loop, 128x128 tile, 4 waves. SWAP=true: mfma(bf,af) -> D rows
// (q4+r) index the (wc,ni) B-tile, cols (l15) index the (wr,mi) A-tile:
//   value acc[mi][ni][r] = C[m = m0+wr*64+mi*16+l15][n = n0+wc*64+ni*16+q4+r]
// -> vector stores along n at fixed m.
// ---------------------------------------------------------------------------
template<bool SWAP>
__device__ __forceinline__ void mfma_panel(f32x4 (&acc)[4][4], const u16* A, const u16* Bm,
                                           int wr, int wc, int l15, int q8) {
  bf16x8 af[4], bf[4];
#pragma unroll
  for (int mi = 0; mi < 4; mi++) af[mi] = *(const bf16x8*)&A[(wr * 64 + mi * 16 + l15) * 32 + q8];
#pragma unroll
  for (int ni = 0; ni < 4; ni++) bf[ni] = *(const bf16x8*)&Bm[(wc * 64 + ni * 16 + l15) * 32 + q8];
#pragma unroll
  for (int mi = 0; mi < 4; mi++)
#pragma unroll
    for (int ni = 0; ni < 4; ni++)
      acc[mi][ni] = SWAP
        ? __builtin_amdgcn_mfma_f32_16x16x32_bf16(bf[ni], af[mi], acc[mi][ni], 0, 0, 0)
        : __builtin_amdgcn_mfma_f32_16x16x32_bf16(af[mi], bf[ni], acc[mi][ni], 0, 0, 0);
}

template<bool SWAP>
__device__ __forceinline__ void gemm_loop(const u16* __restrict__ X, const u16* __restrict__ W,
                                          int m0, int n0, int K,
                                          u16* As, u16* Bs, f32x4 (&acc)[4][4], int tid) {
  const int wave = tid >> 6, lane = tid & 63;
  const int wr = wave >> 1, wc = wave & 1, l15 = lane & 15, q8 = (lane >> 4) * 8;
  const u16* Ap = X + (size_t)(m0 + wave * 32 + (lane >> 2)) * K + (lane & 3) * 8;
  const u16* Bp = W + (size_t)(n0 + wave * 32 + (lane >> 2)) * K + (lane & 3) * 8;
  u16* A0 = As + wave * 1024;
  u16* B0 = Bs + wave * 1024;
  for (int k0 = 0; k0 < K; k0 += 64) {
    GLDS(Ap + k0,                    A0);
    GLDS(Ap + 16 * (size_t)K + k0,   A0 + 512);
    GLDS(Ap + k0 + 32,               A0 + 4096);
    GLDS(Ap + 16 * (size_t)K + k0 + 32, A0 + 4608);
    GLDS(Bp + k0,                    B0);
    GLDS(Bp + 16 * (size_t)K + k0,   B0 + 512);
    GLDS(Bp + k0 + 32,               B0 + 4096);
    GLDS(Bp + 16 * (size_t)K + k0 + 32, B0 + 4608);
    __syncthreads();
    mfma_panel<SWAP>(acc, As, Bs, wr, wc, l15, q8);
    mfma_panel<SWAP>(acc, As + 4096, Bs + 4096, wr, wc, l15, q8);
    __syncthreads();
  }
}

// ---------------------------------------------------------------------------
// Mega-GEMM: X[M,1024] @ Wcat[3456,1024]^T.
//  ny 0-7   (swapped): silu -> Qb u16x4
//  ny 8-15  (swapped): silu -> Kb u16x4 + KT via LDS scalar-transpose
//  ny 16-23 (unswapped): -> VT direct u16x4 (C/D rows run along m = seq dim)
//  ny 24-25 (swapped): -> T1 u16x4
//  ny 26    (swapped): f logits -> LOGF
// ---------------------------------------------------------------------------
__global__ void __launch_bounds__(256) mega_gemm(const u16* __restrict__ X, const u16* __restrict__ Wcat,
                                                 const float* __restrict__ llb,
                                                 u16* __restrict__ Qb, u16* __restrict__ Kb,
                                                 u16* __restrict__ KT, u16* __restrict__ VT,
                                                 u16* __restrict__ T1, float* __restrict__ LOGF) {
  __shared__ u16 sh[17408];           // As=sh, Bs=sh+8192; Ts overlays (stride 136)
  u16* As = sh;
  u16* Bs = sh + 8192;
  u16* Ts = sh;
  const int tid = threadIdx.x;
  const int m0 = blockIdx.x * 128;
  const int ny = blockIdx.y, n0 = ny * 128;
  const int wave = tid >> 6, lane = tid & 63;
  const int wr = wave >> 1, wc = wave & 1, l15 = lane & 15, q4 = (lane >> 4) * 4;
  f32x4 acc[4][4];
#pragma unroll
  for (int i = 0; i < 4; i++)
#pragma unroll
    for (int j = 0; j < 4; j++) acc[i][j] = (f32x4){0.f, 0.f, 0.f, 0.f};

  if (ny >= 16 && ny < 24) {
    // ---- V block: unswapped -> rows (q4+r) = m-dim -> direct u16x4 into VT ----
    gemm_loop<false>(X, Wcat, m0, n0, 1024, As, Bs, acc, tid);
#pragma unroll
    for (int mi = 0; mi < 4; mi++) {
#pragma unroll
      for (int ni = 0; ni < 4; ni++) {
        int col = n0 - 2048 + wc * 64 + ni * 16 + l15;   // v-dim 0..1023
        int rbase = m0 + wr * 64 + mi * 16 + q4;         // m-dim (4 consecutive)
        int head = col >> 7, rl = col & 127;
        int bb = rbase >> 12, nseq = rbase & (N_ - 1);
        u16x4 pk;
#pragma unroll
        for (int r = 0; r < 4; r++) pk[r] = f2b(acc[mi][ni][r]);
        *(u16x4*)&VT[((size_t)(bb * H_ + head) * R_ + rl) * N_ + nseq] = pk;
      }
    }
    return;
  }

  gemm_loop<true>(X, Wcat, m0, n0, 1024, As, Bs, acc, tid);

  if (ny == 26) {                     // decay logits -> LOGF
    // n-local = wc*64 + ni*16 + q4 + r must be < 8  =>  wc==0, ni==0, q4 in {0,4}
    if (wc == 0 && (lane >> 4) < 2) {
#pragma unroll
      for (int mi = 0; mi < 4; mi++) {
        int mcol = m0 + wr * 64 + mi * 16 + l15;
        int bb = mcol >> 12, nseq = mcol & (N_ - 1);
#pragma unroll
        for (int r = 0; r < 4; r++) {
          int h = q4 + r;             // 0..7
          float lb = __expf(llb[h]);
          LOGF[(size_t)(bb * H_ + h) * N_ + nseq] =
              __logf(lb + (1.f - lb) * sigm(acc[mi][0][r]));
        }
      }
    }
    return;
  }

  // swapped: lane holds 4 consecutive n (nb..nb+3) at fixed m (mcol)
#pragma unroll
  for (int mi = 0; mi < 4; mi++) {
#pragma unroll
    for (int ni = 0; ni < 4; ni++) {
      int nb = n0 + wc * 64 + ni * 16 + q4;
      int mcol = m0 + wr * 64 + mi * 16 + l15;
      u16x4 pk;
#pragma unroll
      for (int r = 0; r < 4; r++) {
        float v = acc[mi][ni][r];
        if (ny < 16) v = v * sigm(v);
        pk[r] = f2b(v);
      }
      if (ny < 8) {
        *(u16x4*)&Qb[(size_t)mcol * E_ + nb] = pk;
      } else if (ny < 16) {
        *(u16x4*)&Kb[(size_t)mcol * E_ + nb - 1024] = pk;
        int nl = nb - n0;             // local k-dim 0..127
        int ml = mcol - m0;           // local m 0..127
#pragma unroll
        for (int r = 0; r < 4; r++) Ts[(nl + r) * 136 + ml] = pk[r];
      } else {                        // ny 24/25 -> T1
        *(u16x4*)&T1[(size_t)mcol * 256 + nb - 3072] = pk;
      }
    }
  }

  if (ny >= 8 && ny < 16) {           // KT copy-out from Ts[nl][ml]
    __syncthreads();
    int head = (n0 - 1024) >> 7;
    int bb = m0 >> 12, nloc = m0 & (N_ - 1);
    size_t base = ((size_t)(bb * H_ + head) * R_) * N_ + nloc;
#pragma unroll
    for (int p = 0; p < 8; p++) {
      int nl = p * 16 + (tid >> 4);
      int m8 = (tid & 15) * 8;
      u16x8 v = *(const u16x8*)&Ts[nl * 136 + m8];
      *(u16x8*)&KT[base + (size_t)nl * N_ + m8] = v;
    }
  }
}

// ---------------------------------------------------------------------------
// beta+gate GEMM (swapped): T1[M,256] @ Wcat2[2048,256]^T.
// ---------------------------------------------------------------------------
__global__ void __launch_bounds__(256) bg_gemm(const u16* __restrict__ T1, const u16* __restrict__ W2,
                                               u16* __restrict__ BETA, u16* __restrict__ GATE) {
  __shared__ u16 As[8192];
  __shared__ u16 Bs[8192];
  const int tid = threadIdx.x;
  const int m0 = blockIdx.x * 128;
  const int n0 = blockIdx.y * 128;
  f32x4 acc[4][4];
#pragma unroll
  for (int i = 0; i < 4; i++)
#pragma unroll
    for (int j = 0; j < 4; j++) acc[i][j] = (f32x4){0.f, 0.f, 0.f, 0.f};
  gemm_loop<true>(T1, W2, m0, n0, 256, As, Bs, acc, tid);
  const int wave = tid >> 6, lane = tid & 63;
  const int wr = wave >> 1, wc = wave & 1, l15 = lane & 15, q4 = (lane >> 4) * 4;
#pragma unroll
  for (int mi = 0; mi < 4; mi++) {
#pragma unroll
    for (int ni = 0; ni < 4; ni++) {
      int nb = n0 + wc * 64 + ni * 16 + q4;
      int mcol = m0 + wr * 64 + mi * 16 + l15;
      u16x4 pk;
      if (nb < 1024) {
#pragma unroll
        for (int r = 0; r < 4; r++) {
          float v = acc[mi][ni][r];
          pk[r] = f2b(v * sigm(v));
        }
        *(u16x4*)&BETA[(size_t)mcol * E_ + nb] = pk;
      } else {
#pragma unroll
        for (int r = 0; r < 4; r++) pk[r] = f2b(sigm(acc[mi][ni][r]));
        *(u16x4*)&GATE[(size_t)mcol * E_ + nb - 1024] = pk;
      }
    }
  }
}

// ---------------------------------------------------------------------------
// Output GEMM (swapped): OLN[M,1024] @ Wo[1024,1024]^T -> fp32 out, float4.
// ---------------------------------------------------------------------------
__global__ void __launch_bounds__(256) out_gemm(const u16* __restrict__ X, const u16* __restrict__ W,
                                                float* __restrict__ C) {
  __shared__ u16 As[8192];
  __shared__ u16 Bs[8192];
  const int tid = threadIdx.x;
  const int m0 = blockIdx.x * 128;
  const int n0 = blockIdx.y * 128;
  f32x4 acc[4][4];
#pragma unroll
  for (int i = 0; i < 4; i++)
#pragma unroll
    for (int j = 0; j < 4; j++) acc[i][j] = (f32x4){0.f, 0.f, 0.f, 0.f};
  gemm_loop<true>(X, W, m0, n0, 1024, As, Bs, acc, tid);
  const int wave = tid >> 6, lane = tid & 63;
  const int wr = wave >> 1, wc = wave & 1, l15 = lane & 15, q4 = (lane >> 4) * 4;
#pragma unroll
  for (int mi = 0; mi < 4; mi++) {
#pragma unroll
    for (int ni = 0; ni < 4; ni++) {
      int nb = n0 + wc * 64 + ni * 16 + q4;
      int mcol = m0 + wr * 64 + mi * 16 + l15;
      *(f32x4*)&C[(size_t)mcol * E_ + nb] = acc[mi][ni];
    }
  }
}

// ---------------------------------------------------------------------------
// Householder on bf16 q (in place)
// ---------------------------------------------------------------------------
__global__ void __launch_bounds__(256) householder(u16* __restrict__ Q, const u16* __restrict__ BETA) {
  int row = blockIdx.x;
  int tid = threadIdx.x;
  u16* q = Q + (size_t)row * E_;
  const u16* bt = BETA + (size_t)row * E_;
  u16x4 q4 = *(const u16x4*)(q + tid * 4);
  u16x4 b4 = *(const u16x4*)(bt + tid * 4);
  float qv[4], bv[4];
#pragma unroll
  for (int i = 0; i < 4; i++) { qv[i] = b2f(q4[i]); bv[i] = b2f(b4[i]); }
  float ss = bv[0]*bv[0] + bv[1]*bv[1] + bv[2]*bv[2] + bv[3]*bv[3];
  float qd = qv[0]*bv[0] + qv[1]*bv[1] + qv[2]*bv[2] + qv[3]*bv[3];
  __shared__ float red[8];
#pragma unroll
  for (int m = 1; m < 64; m <<= 1) { ss += __shfl_xor(ss, m); qd += __shfl_xor(qd, m); }
  int wid = tid >> 6;
  if ((tid & 63) == 0) { red[wid] = ss; red[4 + wid] = qd; }
  __syncthreads();
  ss = red[0] + red[1] + red[2] + red[3];
  qd = red[4] + red[5] + red[6] + red[7];
  float coef = 2.f * qd / (ss + 1e-12f);
  const float scale = 0.08838834764831845f;  // 128^-0.5 folded in
  u16x4 o4;
#pragma unroll
  for (int i = 0; i < 4; i++) o4[i] = f2b((qv[i] - coef * bv[i]) * scale);
  *(u16x4*)(q + tid * 4) = o4;
}

// inclusive scan of the 128 log-decay values of one chunk into cum[] (wave 0)
__device__ __forceinline__ void scan_chunk(const float* __restrict__ lf, float* cum, int tid) {
  if (tid < 64) {
    float a = lf[tid], b = lf[tid + 64];
#pragma unroll
    for (int off = 1; off < 64; off <<= 1) {
      float t = __shfl_up(a, off);  if (tid >= off) a += t;
      float t2 = __shfl_up(b, off); if (tid >= off) b += t2;
    }
    b += __shfl(a, 63);
    cum[tid] = a; cum[tid + 64] = b;
  }
  __syncthreads();
}

// stage a [128 x 32] bf16 slab (row stride `stride` elements) into LDS [128][40]
__device__ __forceinline__ void stage32(u16* dst, const u16* src, size_t stride, int tid) {
  int r0 = tid >> 2, c8 = (tid & 3) * 8;
  *(u16x8*)&dst[(size_t)r0 * 40 + c8] = *(const u16x8*)&src[(size_t)r0 * stride + c8];
  int r1 = r0 + 64;
  *(u16x8*)&dst[(size_t)r1 * 40 + c8] = *(const u16x8*)&src[(size_t)r1 * stride + c8];
}

// same, scaling column j (slab-local) by w[j0 + j]
__device__ __forceinline__ void stage32_scaled(u16* dst, const u16* src, size_t stride,
                                               const float* w, int j0, int tid) {
  int c8 = (tid & 3) * 8;
  float wv[8];
#pragma unroll
  for (int i = 0; i < 8; i++) wv[i] = w[j0 + c8 + i];
#pragma unroll
  for (int rr = 0; rr < 128; rr += 64) {
    int r = rr + (tid >> 2);
    u16x8 raw = *(const u16x8*)&src[(size_t)r * stride + c8];
    u16x8 o;
#pragma unroll
    for (int i = 0; i < 8; i++) o[i] = f2b(b2f(raw[i]) * wv[i]);
    *(u16x8*)&dst[(size_t)r * 40 + c8] = o;
  }
}

// one K=32 MFMA step over a 128x128 output (4 waves), A/B slabs in LDS [128][40]
template<bool SWAP>
__device__ __forceinline__ void mfma16(f32x4 (&acc)[4][4], const u16* A, const u16* Bm,
                                       int wr, int wc, int l15, int q8) {
  bf16x8 af[4], bf[4];
#pragma unroll
  for (int mi = 0; mi < 4; mi++) af[mi] = *(const bf16x8*)&A[(wr * 64 + mi * 16 + l15) * 40 + q8];
#pragma unroll
  for (int ni = 0; ni < 4; ni++) bf[ni] = *(const bf16x8*)&Bm[(wc * 64 + ni * 16 + l15) * 40 + q8];
#pragma unroll
  for (int mi = 0; mi < 4; mi++)
#pragma unroll
    for (int ni = 0; ni < 4; ni++)
      acc[mi][ni] = SWAP
        ? __builtin_amdgcn_mfma_f32_16x16x32_bf16(bf[ni], af[mi], acc[mi][ni], 0, 0, 0)
        : __builtin_amdgcn_mfma_f32_16x16x32_bf16(af[mi], bf[ni], acc[mi][ni], 0, 0, 0);
}

// ---------------------------------------------------------------------------
// Phase A (MFMA, swapped): acc[mi][ni][r] = D[k = wc*64+ni*16+q4+r][v = wr*64+mi*16+l15]
// = sum_j KTw[k][j] VT[v][j]  ->  float4 store at U[v][k..k+3].
// ---------------------------------------------------------------------------
__global__ void __launch_bounds__(256) gla_phaseA(const u16* __restrict__ KT, const u16* __restrict__ VT,
                                                  const float* __restrict__ LOGF,
                                                  float* __restrict__ U, float* __restrict__ DC) {
  const int blk = blockIdx.x;
  const int bh = blk >> 5, c = blk & 31;
  const int tid = threadIdx.x;
  const int wave = tid >> 6, lane = tid & 63;
  const int wr = wave >> 1, wc = wave & 1, l15 = lane & 15, q8 = (lane >> 4) * 8;
  __shared__ u16 SA[128 * 40];
  __shared__ u16 SB[128 * 40];
  __shared__ float cum[CHUNK_];
  __shared__ float wd[CHUNK_];
  scan_chunk(LOGF + (size_t)bh * N_ + c * CHUNK_, cum, tid);
  if (tid < 128) wd[tid] = __expf(cum[127] - cum[tid]);
  __syncthreads();
  const u16* vbase = VT + ((size_t)bh * R_) * N_ + (size_t)c * CHUNK_;
  const u16* kbase = KT + ((size_t)bh * R_) * N_ + (size_t)c * CHUNK_;
  f32x4 acc[4][4];
#pragma unroll
  for (int i = 0; i < 4; i++)
#pragma unroll
    for (int j = 0; j < 4; j++) acc[i][j] = (f32x4){0.f, 0.f, 0.f, 0.f};
  for (int j0 = 0; j0 < CHUNK_; j0 += 32) {
    __syncthreads();
    stage32(SA, vbase + j0, N_, tid);
    stage32_scaled(SB, kbase + j0, N_, wd, j0, tid);
    __syncthreads();
    mfma16<true>(acc, SA, SB, wr, wc, l15, q8);
  }
  float* Up = U + (size_t)blk * (R_ * R_);
  const int q4 = (lane >> 4) * 4;
#pragma unroll
  for (int mi = 0; mi < 4; mi++) {
#pragma unroll
    for (int ni = 0; ni < 4; ni++) {
      int v = wr * 64 + mi * 16 + l15;
      int kb = wc * 64 + ni * 16 + q4;
      *(f32x4*)&Up[(size_t)v * R_ + kb] = acc[mi][ni];
    }
  }
  if (tid == 0) DC[blk] = __expf(cum[127]);
}

// ---------------------------------------------------------------------------
// Phase B: propagate chunk-start states; U fp32 [v][k] -> SS bf16 [v][k]
// ---------------------------------------------------------------------------
__global__ void __launch_bounds__(256) gla_phaseB(const float* __restrict__ U, const float* __restrict__ DC,
                                                  u16* __restrict__ SSb) {
  int idx = blockIdx.x * 256 + threadIdx.x;
  int bh = idx >> 14;
  int e = idx & 16383;
  float s = 0.f;
  for (int c = 0; c < NC_; c++) {
    size_t off = ((size_t)bh * NC_ + c) * 16384 + e;
    SSb[off] = f2b(s);
    s = DC[bh * NC_ + c] * s + U[off];
  }
}

// ---------------------------------------------------------------------------
// Phase C (MFMA): o_i = exp(cum_i)*q_i@Sstart + sum_{j<=i} exp(cum_i-cum_j)(q_i.k_j) v_j
// S^T step unswapped (Ps[i][j] u16x4 writes); term1/term2 swapped -> lane
// holds 4 consecutive v (row=q4) at fixed i (col=l15) -> u16x4 O stores.
// ---------------------------------------------------------------------------
__global__ void __launch_bounds__(256) gla_phaseC(const u16* __restrict__ Qb, const u16* __restrict__ Kb,
                                                  const u16* __restrict__ VT, const u16* __restrict__ SSb,
                                                  const float* __restrict__ LOGF, u16* __restrict__ Ob) {
  const int blk = blockIdx.x;
  const int bh = blk >> 5, c = blk & 31;
  const int b = bh >> 3, h = bh & 7;
  const int tid = threadIdx.x;
  const int wave = tid >> 6, lane = tid & 63;
  const int wr = wave >> 1, wc = wave & 1, l15 = lane & 15;
  const int q4i = (lane >> 4) * 4, q8 = (lane >> 4) * 8;
  __shared__ u16 SA[128 * 40];
  __shared__ u16 SB[128 * 40];
  __shared__ u16 Ps[128 * 136];
  __shared__ float cum[CHUNK_];
  __shared__ float cumE[CHUNK_];
  scan_chunk(LOGF + (size_t)bh * N_ + c * CHUNK_, cum, tid);
  if (tid < 128) cumE[tid] = __expf(cum[tid]);
  __syncthreads();
  const size_t rowbase = ((size_t)(b * N_ + c * CHUNK_)) * E_ + (size_t)h * R_;
  const u16* vtbase = VT + ((size_t)bh * R_) * N_ + (size_t)c * CHUNK_;
  const u16* ssbase = SSb + (size_t)blk * (R_ * R_);

  f32x4 acc[4][4];
#pragma unroll
  for (int i = 0; i < 4; i++)
#pragma unroll
    for (int j = 0; j < 4; j++) acc[i][j] = (f32x4){0.f, 0.f, 0.f, 0.f};

  // ---- S^T = K @ Q^T (row=j, col=i) ----
  for (int r0 = 0; r0 < R_; r0 += 32) {
    __syncthreads();
    stage32(SA, Kb + rowbase + r0, E_, tid);   // rows j
    stage32(SB, Qb + rowbase + r0, E_, tid);   // rows i
    __syncthreads();
    mfma16<false>(acc, SA, SB, wr, wc, l15, q8);
  }
  // ---- mask + decay -> Ps[i][j] ----
#pragma unroll
  for (int mi = 0; mi < 4; mi++) {
#pragma unroll
    for (int ni = 0; ni < 4; ni++) {
      int jb = wr * 64 + mi * 16 + q4i;
      int i = wc * 64 + ni * 16 + l15;
      float ci = cum[i];
      float4 cj = *(const float4*)&cum[jb];
      u16x4 pk;
      float cjv[4] = {cj.x, cj.y, cj.z, cj.w};
#pragma unroll
      for (int r = 0; r < 4; r++) {
        int j = jb + r;
        float w = (j <= i) ? __expf(ci - cjv[r]) : 0.f;
        pk[r] = f2b(acc[mi][ni][r] * w);
      }
      *(u16x4*)&Ps[i * 136 + jb] = pk;
    }
  }
  // ---- term1 (swapped): Q @ SS^T  (row=v, col=i) ----
#pragma unroll
  for (int i = 0; i < 4; i++)
#pragma unroll
    for (int j = 0; j < 4; j++) acc[i][j] = (f32x4){0.f, 0.f, 0.f, 0.f};
  for (int k0 = 0; k0 < R_; k0 += 32) {
    __syncthreads();
    stage32(SA, Qb + rowbase + k0, E_, tid);     // rows i
    stage32(SB, ssbase + k0, R_, tid);           // rows v (SS^T layout [v][k])
    __syncthreads();
    mfma16<true>(acc, SA, SB, wr, wc, l15, q8);
  }
  // scale by exp(cum_i): i = col = wr/mi/l15-mapped -> one scalar per (mi)
#pragma unroll
  for (int mi = 0; mi < 4; mi++) {
    float ei = cumE[wr * 64 + mi * 16 + l15];
#pragma unroll
    for (int ni = 0; ni < 4; ni++)
#pragma unroll
      for (int r = 0; r < 4; r++) acc[mi][ni][r] *= ei;
  }
  // ---- term2 (swapped): acc += P @ V^T (row=v, col=i) ----
  for (int j0 = 0; j0 < CHUNK_; j0 += 32) {
    __syncthreads();
    stage32(SB, vtbase + j0, N_, tid);           // rows v
    __syncthreads();
    if (wr == 1 || j0 < 64) {                    // wr==0 waves: i<64 -> j>=64 all masked
      bf16x8 af[4], bf[4];
#pragma unroll
      for (int mi = 0; mi < 4; mi++)
        af[mi] = *(const bf16x8*)&Ps[(wr * 64 + mi * 16 + l15) * 136 + j0 + q8];
#pragma unroll
      for (int ni = 0; ni < 4; ni++)
        bf[ni] = *(const bf16x8*)&SB[(wc * 64 + ni * 16 + l15) * 40 + q8];
#pragma unroll
      for (int mi = 0; mi < 4; mi++)
#pragma unroll
        for (int ni = 0; ni < 4; ni++)
          acc[mi][ni] = __builtin_amdgcn_mfma_f32_16x16x32_bf16(bf[ni], af[mi], acc[mi][ni], 0, 0, 0);
    }
  }
  // ---- write O (bf16, row-major [m][E]): u16x4 along v at fixed i ----
#pragma unroll
  for (int mi = 0; mi < 4; mi++) {
#pragma unroll
    for (int ni = 0; ni < 4; ni++) {
      int i = wr * 64 + mi * 16 + l15;
      int vb = wc * 64 + ni * 16 + q4i;
      u16x4 pk;
#pragma unroll
      for (int r = 0; r < 4; r++) pk[r] = f2b(acc[mi][ni][r]);
      *(u16x4*)&Ob[rowbase + (size_t)i * E_ + vb] = pk;
    }
  }
}

// ---------------------------------------------------------------------------
// o = o * gate (both bf16); LayerNorm(weight-only, fp32 gamma) -> bf16
// ---------------------------------------------------------------------------
__global__ void __launch_bounds__(256) gate_ln(const u16* __restrict__ O, const u16* __restrict__ G,
                                               const float* __restrict__ gamma, u16* __restrict__ OLN) {
  int row = blockIdx.x, tid = threadIdx.x;
  u16x4 o4 = *(const u16x4*)(O + (size_t)row * E_ + tid * 4);
  u16x4 g4 = *(const u16x4*)(G + (size_t)row * E_ + tid * 4);
  float x0 = b2f(o4[0]) * b2f(g4[0]), x1 = b2f(o4[1]) * b2f(g4[1]);
  float x2 = b2f(o4[2]) * b2f(g4[2]), x3 = b2f(o4[3]) * b2f(g4[3]);
  float s = x0 + x1 + x2 + x3;
  float sq = x0 * x0 + x1 * x1 + x2 * x2 + x3 * x3;
  __shared__ float red[8];
#pragma unroll
  for (int m = 1; m < 64; m <<= 1) { s += __shfl_xor(s, m); sq += __shfl_xor(sq, m); }
  int wid = tid >> 6;
  if ((tid & 63) == 0) { red[wid] = s; red[4 + wid] = sq; }
  __syncthreads();
  s = red[0] + red[1] + red[2] + red[3];
  sq = red[4] + red[5] + red[6] + red[7];
  float mu = s * (1.f / 1024.f);
  float var = sq * (1.f / 1024.f) - mu * mu;
  float rs = rsqrtf(var + 1e-5f);
  int e = tid * 4;
  u16x4 r4;
  r4[0] = f2b((x0 - mu) * rs * gamma[e + 0]);
  r4[1] = f2b((x1 - mu) * rs * gamma[e + 1]);
  r4[2] = f2b((x2 - mu) * rs * gamma[e + 2]);
  r4[3] = f2b((x3 - mu) * rs * gamma[e + 3]);
  *(u16x4*)(OLN + (size_t)row * E_ + e) = r4;
}

// ---------------------------------------------------------------------------
extern "C" void kernel_launch(void* const* d_in, const int* in_sizes, int n_in,
                              void* d_out, int out_size, void* d_ws, size_t ws_size,
                              hipStream_t stream) {
  (void)in_sizes; (void)n_in; (void)out_size; (void)ws_size;
  const float* x   = (const float*)d_in[0];
  const float* llb = (const float*)d_in[1];
  const float* Wq  = (const float*)d_in[2];
  const float* Wk  = (const float*)d_in[3];
  const float* Wv  = (const float*)d_in[4];
  const float* Wf  = (const float*)d_in[5];
  const float* Wb1 = (const float*)d_in[6];
  const float* Wb2 = (const float*)d_in[7];
  const float* Wg1 = (const float*)d_in[8];
  const float* Wg2 = (const float*)d_in[9];
  const float* gm  = (const float*)d_in[10];
  const float* Wo  = (const float*)d_in[11];
  float* out = (float*)d_out;

  char* ws = (char*)d_ws;
  const size_t SZB = (size_t)M_ * E_ * 2;            // 16.78 MB bf16 [M,E]
  u16*   Qb    = (u16*)(ws + 0 * SZB);               // q bf16 (OLN overlay later)
  u16*   Kb    = (u16*)(ws + 1 * SZB);
  u16*   KT    = (u16*)(ws + 2 * SZB);               // [B,H,R,N]
  u16*   VT    = (u16*)(ws + 3 * SZB);               // [B,H,R,N]
  u16*   BETAb = (u16*)(ws + 4 * SZB);               // beta -> O overlay
  u16*   GATEb = (u16*)(ws + 5 * SZB);
  u16*   SSb   = (u16*)(ws + 6 * SZB);               // chunk-start states bf16 [v][k]
  u16*   XB    = (u16*)(ws + 7 * SZB);
  float* U     = (float*)(ws + 8 * SZB);             // fp32 [512][128][128]
  char*  tail  = ws + 8 * SZB + (size_t)BH_ * NC_ * R_ * R_ * 4;
  u16*   Wcat  = (u16*)tail;                         // [3456][1024]
  u16*   Wcat2 = Wcat + (size_t)3456 * 1024;         // [2048][256]
  u16*   WOb   = Wcat2 + (size_t)2048 * 256;         // [1024][1024]
  u16*   T1    = WOb + (size_t)E_ * E_;              // [M,256]
  float* LOGF  = (float*)(T1 + (size_t)M_ * 256);
  float* DC    = LOGF + (size_t)BH_ * N_;
  u16*   Ob    = BETAb;                              // overlay (beta dead after householder)
  u16*   OLN   = Qb;                                 // overlay (q dead after phaseC)

  CvtArgs ca;
  ca.src[0] = x;   ca.dst[0]  = XB;
  ca.src[1] = Wq;  ca.dst[1]  = Wcat;
  ca.src[2] = Wk;  ca.dst[2]  = Wcat + (size_t)1024 * 1024;
  ca.src[3] = Wv;  ca.dst[3]  = Wcat + (size_t)2048 * 1024;
  ca.src[4] = Wf;  ca.dst[4]  = Wcat + (size_t)3328 * 1024;
  ca.src[5] = Wb1; ca.dst[5]  = Wcat + (size_t)3072 * 1024;
  ca.src[6] = Wb2; ca.dst[6]  = Wcat2;
  ca.src[7] = Wg1; ca.dst[7]  = Wcat + (size_t)3200 * 1024;
  ca.src[8] = Wg2; ca.dst[8]  = Wcat2;
  ca.src[9] = Wo;  ca.dst[9]  = WOb;
  ca.dst[10] = Wcat + (size_t)3336 * 1024;           // zero pad rows

  dim3 blk(256);
  cvt_all<<<dim3(12928), blk, 0, stream>>>(ca);
  mega_gemm<<<dim3(64, 27), blk, 0, stream>>>(XB, Wcat, llb, Qb, Kb, KT, VT, T1, LOGF);
  bg_gemm<<<dim3(64, 16), blk, 0, stream>>>(T1, Wcat2, BETAb, GATEb);
  householder<<<dim3(M_), blk, 0, stream>>>(Qb, BETAb);
  gla_phaseA<<<dim3(BH_ * NC_), blk, 0, stream>>>(KT, VT, LOGF, U, DC);
  gla_phaseB<<<dim3(BH_ * 16384 / 256), blk, 0, stream>>>(U, DC, SSb);
  gla_phaseC<<<dim3(BH_ * NC_), blk, 0, stream>>>(Qb, Kb, VT, SSb, LOGF, Ob);
  gate_ln<<<dim3(M_), blk, 0, stream>>>(Ob, GATEb, gm, OLN);
  out_gemm<<<dim3(64, 8), blk, 0, stream>>>(OLN, WOb, out);
}

// Round 8
// 308.280 us; speedup vs baseline: 1.6628x; 1.0271x over previous
//
#include <hip/hip_runtime.h>
#include <hip/hip_bf16.h>

using u16 = unsigned short;
typedef __attribute__((ext_vector_type(8))) short bf16x8;
typedef __attribute__((ext_vector_type(4))) float f32x4;
typedef __attribute__((ext_vector_type(8))) u16 u16x8;
typedef __attribute__((ext_vector_type(4))) u16 u16x4;

#define B_ 2
#define N_ 4096
#define E_ 1024
#define R_ 128
#define H_ 8
#define M_ 8192      // B*N
#define CHUNK_ 128
#define NC_ 32       // N/CHUNK
#define BH_ 16       // B*H

__device__ __forceinline__ float b2f(u16 u) { return __uint_as_float(((unsigned)u) << 16); }
__device__ __forceinline__ u16 f2b(float f) {
  unsigned u = __float_as_uint(f);
  return (u16)((u + 0x7fffu + ((u >> 16) & 1u)) >> 16);   // RNE
}
// fast sigmoid (native v_exp + v_rcp; rel err ~2^-21, fine for bf16 out)
__device__ __forceinline__ float sigm(float x) {
  return __builtin_amdgcn_rcpf(1.0f + __expf(-x));
}

#define GLDS(g, l) __builtin_amdgcn_global_load_lds( \
    (const __attribute__((address_space(1))) unsigned int*)(g), \
    (__attribute__((address_space(3))) unsigned int*)(l), 16, 0, 0)

// ---------------------------------------------------------------------------
// fp32 -> bf16 conversion (x, weights into Wcat/Wcat2/Wo, zero pad).
// ---------------------------------------------------------------------------
struct CvtArgs {
  const float* src[10];
  u16* dst[11];
};

__global__ void __launch_bounds__(256) cvt_all(CvtArgs a) {
  int idx = blockIdx.x * 256 + threadIdx.x;   // float4-granule index; grid exact
  const int SZ[11] = {2097152, 262144, 262144, 262144, 2048,
                      32768, 32768, 32768, 32768, 262144, 30720};
  int off = idx, seg = 0;
#pragma unroll
  for (int i = 0; i < 10; i++) {
    if (seg == i && off >= SZ[i]) { off -= SZ[i]; seg = i + 1; }
  }
  u16x4 z = (u16x4){0, 0, 0, 0};
  if (seg == 10) { ((u16x4*)a.dst[10])[off] = z; return; }   // Wcat pad rows
  float4 v = ((const float4*)a.src[seg])[off];
  u16x4 r;
  r[0] = f2b(v.x); r[1] = f2b(v.y); r[2] = f2b(v.z); r[3] = f2b(v.w);
  if (seg == 6) {              // Wb2 -> Wcat2 rows 0-1023, cols 0-127 (+zero cols 128-255)
    int n = off >> 5, c = off & 31;
    u16x4* W2 = (u16x4*)a.dst[6];
    W2[n * 64 + c] = r; W2[n * 64 + 32 + c] = z;
  } else if (seg == 8) {       // Wg2 -> Wcat2 rows 1024-2047, cols 128-255 (+zero cols 0-127)
    int n = off >> 5, c = off & 31;
    u16x4* W2 = (u16x4*)a.dst[8];
    W2[(1024 + n) * 64 + 32 + c] = r; W2[(1024 + n) * 64 + c] = z;
  } else {
    ((u16x4*)a.dst[seg])[off] = r;
  }
}

// ---------------------------------------------------------------------------
// BK=64 GEMM K-loop, 128x128 tile, 4 waves, compile-time K (full unroll ->
// constant-folded addressing). SWAP=true: mfma(bf,af) -> D rows (q4+r) index
// the (wc,ni) B-tile, cols (l15) index the (wr,mi) A-tile:
//   acc[mi][ni][r] = C[m = m0+wr*64+mi*16+l15][n = n0+wc*64+ni*16+q4+r]
// ---------------------------------------------------------------------------
template<bool SWAP>
__device__ __forceinline__ void mfma_panel(f32x4 (&acc)[4][4], const u16* A, const u16* Bm,
                                           int wr, int wc, int l15, int q8) {
  bf16x8 af[4], bf[4];
#pragma unroll
  for (int mi = 0; mi < 4; mi++) af[mi] = *(const bf16x8*)&A[(wr * 64 + mi * 16 + l15) * 32 + q8];
#pragma unroll
  for (int ni = 0; ni < 4; ni++) bf[ni] = *(const bf16x8*)&Bm[(wc * 64 + ni * 16 + l15) * 32 + q8];
#pragma unroll
  for (int mi = 0; mi < 4; mi++)
#pragma unroll
    for (int ni = 0; ni < 4; ni++)
      acc[mi][ni] = SWAP
        ? __builtin_amdgcn_mfma_f32_16x16x32_bf16(bf[ni], af[mi], acc[mi][ni], 0, 0, 0)
        : __builtin_amdgcn_mfma_f32_16x16x32_bf16(af[mi], bf[ni], acc[mi][ni], 0, 0, 0);
}

template<bool SWAP, int K>
__device__ __forceinline__ void gemm_loop(const u16* __restrict__ X, const u16* __restrict__ W,
                                          int m0, int n0,
                                          u16* As, u16* Bs, f32x4 (&acc)[4][4], int tid) {
  const int wave = tid >> 6, lane = tid & 63;
  const int wr = wave >> 1, wc = wave & 1, l15 = lane & 15, q8 = (lane >> 4) * 8;
  const u16* Ap = X + (size_t)(m0 + wave * 32 + (lane >> 2)) * K + (lane & 3) * 8;
  const u16* Bp = W + (size_t)(n0 + wave * 32 + (lane >> 2)) * K + (lane & 3) * 8;
  u16* A0 = As + wave * 1024;
  u16* B0 = Bs + wave * 1024;
#pragma unroll
  for (int k0 = 0; k0 < K; k0 += 64) {
    GLDS(Ap + k0,                    A0);
    GLDS(Ap + 16 * (size_t)K + k0,   A0 + 512);
    GLDS(Ap + k0 + 32,               A0 + 4096);
    GLDS(Ap + 16 * (size_t)K + k0 + 32, A0 + 4608);
    GLDS(Bp + k0,                    B0);
    GLDS(Bp + 16 * (size_t)K + k0,   B0 + 512);
    GLDS(Bp + k0 + 32,               B0 + 4096);
    GLDS(Bp + 16 * (size_t)K + k0 + 32, B0 + 4608);
    __syncthreads();
    mfma_panel<SWAP>(acc, As, Bs, wr, wc, l15, q8);
    mfma_panel<SWAP>(acc, As + 4096, Bs + 4096, wr, wc, l15, q8);
    __syncthreads();
  }
}

// ---------------------------------------------------------------------------
// Mega-GEMM: X[M,1024] @ Wcat[3456,1024]^T. Grid (27, 64): x = ny (so
// concurrent blocks share Wcat columns in L2), y = m-tile.
//  ny 0-7   (swapped): silu -> Qb u16x4
//  ny 8-15  (swapped): silu -> Kb u16x4 + KT via LDS scalar-transpose
//  ny 16-23 (unswapped): -> VT direct u16x4 (C/D rows run along m = seq dim)
//  ny 24-25 (swapped): -> T1 u16x4
//  ny 26    (swapped): f logits -> LOGF
// ---------------------------------------------------------------------------
__global__ void __launch_bounds__(256) mega_gemm(const u16* __restrict__ X, const u16* __restrict__ Wcat,
                                                 const float* __restrict__ llb,
                                                 u16* __restrict__ Qb, u16* __restrict__ Kb,
                                                 u16* __restrict__ KT, u16* __restrict__ VT,
                                                 u16* __restrict__ T1, float* __restrict__ LOGF) {
  __shared__ u16 sh[17408];           // As=sh, Bs=sh+8192; Ts overlays (stride 136)
  u16* As = sh;
  u16* Bs = sh + 8192;
  u16* Ts = sh;
  const int tid = threadIdx.x;
  const int m0 = blockIdx.y * 128;
  const int ny = blockIdx.x, n0 = ny * 128;
  const int wave = tid >> 6, lane = tid & 63;
  const int wr = wave >> 1, wc = wave & 1, l15 = lane & 15, q4 = (lane >> 4) * 4;
  f32x4 acc[4][4];
#pragma unroll
  for (int i = 0; i < 4; i++)
#pragma unroll
    for (int j = 0; j < 4; j++) acc[i][j] = (f32x4){0.f, 0.f, 0.f, 0.f};

  if (ny >= 16 && ny < 24) {
    // ---- V block: unswapped -> rows (q4+r) = m-dim -> direct u16x4 into VT ----
    gemm_loop<false, 1024>(X, Wcat, m0, n0, As, Bs, acc, tid);
#pragma unroll
    for (int mi = 0; mi < 4; mi++) {
#pragma unroll
      for (int ni = 0; ni < 4; ni++) {
        int col = n0 - 2048 + wc * 64 + ni * 16 + l15;   // v-dim 0..1023
        int rbase = m0 + wr * 64 + mi * 16 + q4;         // m-dim (4 consecutive)
        int head = col >> 7, rl = col & 127;
        int bb = rbase >> 12, nseq = rbase & (N_ - 1);
        u16x4 pk;
#pragma unroll
        for (int r = 0; r < 4; r++) pk[r] = f2b(acc[mi][ni][r]);
        *(u16x4*)&VT[((size_t)(bb * H_ + head) * R_ + rl) * N_ + nseq] = pk;
      }
    }
    return;
  }

  gemm_loop<true, 1024>(X, Wcat, m0, n0, As, Bs, acc, tid);

  if (ny == 26) {                     // decay logits -> LOGF
    // n-local = wc*64 + ni*16 + q4 + r < 8  =>  wc==0, ni==0, q4 in {0,4}
    if (wc == 0 && (lane >> 4) < 2) {
#pragma unroll
      for (int mi = 0; mi < 4; mi++) {
        int mcol = m0 + wr * 64 + mi * 16 + l15;
        int bb = mcol >> 12, nseq = mcol & (N_ - 1);
#pragma unroll
        for (int r = 0; r < 4; r++) {
          int h = q4 + r;             // 0..7
          float lb = __expf(llb[h]);
          LOGF[(size_t)(bb * H_ + h) * N_ + nseq] =
              __logf(lb + (1.f - lb) * sigm(acc[mi][0][r]));
        }
      }
    }
    return;
  }

  // swapped: lane holds 4 consecutive n (nb..nb+3) at fixed m (mcol)
#pragma unroll
  for (int mi = 0; mi < 4; mi++) {
#pragma unroll
    for (int ni = 0; ni < 4; ni++) {
      int nb = n0 + wc * 64 + ni * 16 + q4;
      int mcol = m0 + wr * 64 + mi * 16 + l15;
      u16x4 pk;
#pragma unroll
      for (int r = 0; r < 4; r++) {
        float v = acc[mi][ni][r];
        if (ny < 16) v = v * sigm(v);
        pk[r] = f2b(v);
      }
      if (ny < 8) {
        *(u16x4*)&Qb[(size_t)mcol * E_ + nb] = pk;
      } else if (ny < 16) {
        *(u16x4*)&Kb[(size_t)mcol * E_ + nb - 1024] = pk;
        int nl = nb - n0;             // local k-dim 0..127
        int ml = mcol - m0;           // local m 0..127
#pragma unroll
        for (int r = 0; r < 4; r++) Ts[(nl + r) * 136 + ml] = pk[r];
      } else {                        // ny 24/25 -> T1
        *(u16x4*)&T1[(size_t)mcol * 256 + nb - 3072] = pk;
      }
    }
  }

  if (ny >= 8 && ny < 16) {           // KT copy-out from Ts[nl][ml]
    __syncthreads();
    int head = (n0 - 1024) >> 7;
    int bb = m0 >> 12, nloc = m0 & (N_ - 1);
    size_t base = ((size_t)(bb * H_ + head) * R_) * N_ + nloc;
#pragma unroll
    for (int p = 0; p < 8; p++) {
      int nl = p * 16 + (tid >> 4);
      int m8 = (tid & 15) * 8;
      u16x8 v = *(const u16x8*)&Ts[nl * 136 + m8];
      *(u16x8*)&KT[base + (size_t)nl * N_ + m8] = v;
    }
  }
}

// ---------------------------------------------------------------------------
// beta+gate GEMM (swapped): T1[M,256] @ Wcat2[2048,256]^T.
// ---------------------------------------------------------------------------
__global__ void __launch_bounds__(256) bg_gemm(const u16* __restrict__ T1, const u16* __restrict__ W2,
                                               u16* __restrict__ BETA, u16* __restrict__ GATE) {
  __shared__ u16 As[8192];
  __shared__ u16 Bs[8192];
  const int tid = threadIdx.x;
  const int m0 = blockIdx.x * 128;
  const int n0 = blockIdx.y * 128;
  f32x4 acc[4][4];
#pragma unroll
  for (int i = 0; i < 4; i++)
#pragma unroll
    for (int j = 0; j < 4; j++) acc[i][j] = (f32x4){0.f, 0.f, 0.f, 0.f};
  gemm_loop<true, 256>(T1, W2, m0, n0, As, Bs, acc, tid);
  const int wave = tid >> 6, lane = tid & 63;
  const int wr = wave >> 1, wc = wave & 1, l15 = lane & 15, q4 = (lane >> 4) * 4;
#pragma unroll
  for (int mi = 0; mi < 4; mi++) {
#pragma unroll
    for (int ni = 0; ni < 4; ni++) {
      int nb = n0 + wc * 64 + ni * 16 + q4;
      int mcol = m0 + wr * 64 + mi * 16 + l15;
      u16x4 pk;
      if (nb < 1024) {
#pragma unroll
        for (int r = 0; r < 4; r++) {
          float v = acc[mi][ni][r];
          pk[r] = f2b(v * sigm(v));
        }
        *(u16x4*)&BETA[(size_t)mcol * E_ + nb] = pk;
      } else {
#pragma unroll
        for (int r = 0; r < 4; r++) pk[r] = f2b(sigm(acc[mi][ni][r]));
        *(u16x4*)&GATE[(size_t)mcol * E_ + nb - 1024] = pk;
      }
    }
  }
}

// ---------------------------------------------------------------------------
// Output GEMM (swapped): OLN[M,1024] @ Wo[1024,1024]^T -> fp32 out, float4.
// ---------------------------------------------------------------------------
__global__ void __launch_bounds__(256) out_gemm(const u16* __restrict__ X, const u16* __restrict__ W,
                                                float* __restrict__ C) {
  __shared__ u16 As[8192];
  __shared__ u16 Bs[8192];
  const int tid = threadIdx.x;
  const int m0 = blockIdx.x * 128;
  const int n0 = blockIdx.y * 128;
  f32x4 acc[4][4];
#pragma unroll
  for (int i = 0; i < 4; i++)
#pragma unroll
    for (int j = 0; j < 4; j++) acc[i][j] = (f32x4){0.f, 0.f, 0.f, 0.f};
  gemm_loop<true, 1024>(X, W, m0, n0, As, Bs, acc, tid);
  const int wave = tid >> 6, lane = tid & 63;
  const int wr = wave >> 1, wc = wave & 1, l15 = lane & 15, q4 = (lane >> 4) * 4;
#pragma unroll
  for (int mi = 0; mi < 4; mi++) {
#pragma unroll
    for (int ni = 0; ni < 4; ni++) {
      int nb = n0 + wc * 64 + ni * 16 + q4;
      int mcol = m0 + wr * 64 + mi * 16 + l15;
      *(f32x4*)&C[(size_t)mcol * E_ + nb] = acc[mi][ni];
    }
  }
}

// ---------------------------------------------------------------------------
// Householder on bf16 q (in place)
// ---------------------------------------------------------------------------
__global__ void __launch_bounds__(256) householder(u16* __restrict__ Q, const u16* __restrict__ BETA) {
  int row = blockIdx.x;
  int tid = threadIdx.x;
  u16* q = Q + (size_t)row * E_;
  const u16* bt = BETA + (size_t)row * E_;
  u16x4 q4 = *(const u16x4*)(q + tid * 4);
  u16x4 b4 = *(const u16x4*)(bt + tid * 4);
  float qv[4], bv[4];
#pragma unroll
  for (int i = 0; i < 4; i++) { qv[i] = b2f(q4[i]); bv[i] = b2f(b4[i]); }
  float ss = bv[0]*bv[0] + bv[1]*bv[1] + bv[2]*bv[2] + bv[3]*bv[3];
  float qd = qv[0]*bv[0] + qv[1]*bv[1] + qv[2]*bv[2] + qv[3]*bv[3];
  __shared__ float red[8];
#pragma unroll
  for (int m = 1; m < 64; m <<= 1) { ss += __shfl_xor(ss, m); qd += __shfl_xor(qd, m); }
  int wid = tid >> 6;
  if ((tid & 63) == 0) { red[wid] = ss; red[4 + wid] = qd; }
  __syncthreads();
  ss = red[0] + red[1] + red[2] + red[3];
  qd = red[4] + red[5] + red[6] + red[7];
  float coef = 2.f * qd / (ss + 1e-12f);
  const float scale = 0.08838834764831845f;  // 128^-0.5 folded in
  u16x4 o4;
#pragma unroll
  for (int i = 0; i < 4; i++) o4[i] = f2b((qv[i] - coef * bv[i]) * scale);
  *(u16x4*)(q + tid * 4) = o4;
}

// inclusive scan of the 128 log-decay values of one chunk into cum[] (wave 0)
__device__ __forceinline__ void scan_chunk(const float* __restrict__ lf, float* cum, int tid) {
  if (tid < 64) {
    float a = lf[tid], b = lf[tid + 64];
#pragma unroll
    for (int off = 1; off < 64; off <<= 1) {
      float t = __shfl_up(a, off);  if (tid >= off) a += t;
      float t2 = __shfl_up(b, off); if (tid >= off) b += t2;
    }
    b += __shfl(a, 63);
    cum[tid] = a; cum[tid + 64] = b;
  }
  __syncthreads();
}

// stage a [128 x 32] bf16 slab (row stride `stride` elements) into LDS [128][40]
__device__ __forceinline__ void stage32(u16* dst, const u16* src, size_t stride, int tid) {
  int r0 = tid >> 2, c8 = (tid & 3) * 8;
  *(u16x8*)&dst[(size_t)r0 * 40 + c8] = *(const u16x8*)&src[(size_t)r0 * stride + c8];
  int r1 = r0 + 64;
  *(u16x8*)&dst[(size_t)r1 * 40 + c8] = *(const u16x8*)&src[(size_t)r1 * stride + c8];
}

// same, scaling column j (slab-local) by w[j0 + j]
__device__ __forceinline__ void stage32_scaled(u16* dst, const u16* src, size_t stride,
                                               const float* w, int j0, int tid) {
  int c8 = (tid & 3) * 8;
  float wv[8];
#pragma unroll
  for (int i = 0; i < 8; i++) wv[i] = w[j0 + c8 + i];
#pragma unroll
  for (int rr = 0; rr < 128; rr += 64) {
    int r = rr + (tid >> 2);
    u16x8 raw = *(const u16x8*)&src[(size_t)r * stride + c8];
    u16x8 o;
#pragma unroll
    for (int i = 0; i < 8; i++) o[i] = f2b(b2f(raw[i]) * wv[i]);
    *(u16x8*)&dst[(size_t)r * 40 + c8] = o;
  }
}

// one K=32 MFMA step over a 128x128 output (4 waves), A/B slabs in LDS [128][40]
template<bool SWAP>
__device__ __forceinline__ void mfma16(f32x4 (&acc)[4][4], const u16* A, const u16* Bm,
                                       int wr, int wc, int l15, int q8) {
  bf16x8 af[4], bf[4];
#pragma unroll
  for (int mi = 0; mi < 4; mi++) af[mi] = *(const bf16x8*)&A[(wr * 64 + mi * 16 + l15) * 40 + q8];
#pragma unroll
  for (int ni = 0; ni < 4; ni++) bf[ni] = *(const bf16x8*)&Bm[(wc * 64 + ni * 16 + l15) * 40 + q8];
#pragma unroll
  for (int mi = 0; mi < 4; mi++)
#pragma unroll
    for (int ni = 0; ni < 4; ni++)
      acc[mi][ni] = SWAP
        ? __builtin_amdgcn_mfma_f32_16x16x32_bf16(bf[ni], af[mi], acc[mi][ni], 0, 0, 0)
        : __builtin_amdgcn_mfma_f32_16x16x32_bf16(af[mi], bf[ni], acc[mi][ni], 0, 0, 0);
}

// ---------------------------------------------------------------------------
// Phase A (MFMA, swapped): acc[mi][ni][r] = D[k = wc*64+ni*16+q4+r][v = wr*64+mi*16+l15]
// = sum_j KTw[k][j] VT[v][j]  ->  u16x4 (bf16) store at U[v][k..k+3].
// ---------------------------------------------------------------------------
__global__ void __launch_bounds__(256) gla_phaseA(const u16* __restrict__ KT, const u16* __restrict__ VT,
                                                  const float* __restrict__ LOGF,
                                                  u16* __restrict__ U, float* __restrict__ DC) {
  const int blk = blockIdx.x;
  const int bh = blk >> 5, c = blk & 31;
  const int tid = threadIdx.x;
  const int wave = tid >> 6, lane = tid & 63;
  const int wr = wave >> 1, wc = wave & 1, l15 = lane & 15, q8 = (lane >> 4) * 8;
  __shared__ u16 SA[128 * 40];
  __shared__ u16 SB[128 * 40];
  __shared__ float cum[CHUNK_];
  __shared__ float wd[CHUNK_];
  scan_chunk(LOGF + (size_t)bh * N_ + c * CHUNK_, cum, tid);
  if (tid < 128) wd[tid] = __expf(cum[127] - cum[tid]);
  __syncthreads();
  const u16* vbase = VT + ((size_t)bh * R_) * N_ + (size_t)c * CHUNK_;
  const u16* kbase = KT + ((size_t)bh * R_) * N_ + (size_t)c * CHUNK_;
  f32x4 acc[4][4];
#pragma unroll
  for (int i = 0; i < 4; i++)
#pragma unroll
    for (int j = 0; j < 4; j++) acc[i][j] = (f32x4){0.f, 0.f, 0.f, 0.f};
  for (int j0 = 0; j0 < CHUNK_; j0 += 32) {
    __syncthreads();
    stage32(SA, vbase + j0, N_, tid);
    stage32_scaled(SB, kbase + j0, N_, wd, j0, tid);
    __syncthreads();
    mfma16<true>(acc, SA, SB, wr, wc, l15, q8);
  }
  u16* Up = U + (size_t)blk * (R_ * R_);
  const int q4 = (lane >> 4) * 4;
#pragma unroll
  for (int mi = 0; mi < 4; mi++) {
#pragma unroll
    for (int ni = 0; ni < 4; ni++) {
      int v = wr * 64 + mi * 16 + l15;
      int kb = wc * 64 + ni * 16 + q4;
      u16x4 pk;
#pragma unroll
      for (int r = 0; r < 4; r++) pk[r] = f2b(acc[mi][ni][r]);
      *(u16x4*)&Up[(size_t)v * R_ + kb] = pk;
    }
  }
  if (tid == 0) DC[blk] = __expf(cum[127]);
}

// ---------------------------------------------------------------------------
// Phase B: propagate chunk-start states; U bf16 [v][k] -> SS bf16 [v][k]
// ---------------------------------------------------------------------------
__global__ void __launch_bounds__(256) gla_phaseB(const u16* __restrict__ U, const float* __restrict__ DC,
                                                  u16* __restrict__ SSb) {
  int idx = blockIdx.x * 256 + threadIdx.x;
  int bh = idx >> 14;
  int e = idx & 16383;
  float s = 0.f;
  for (int c = 0; c < NC_; c++) {
    size_t off = ((size_t)bh * NC_ + c) * 16384 + e;
    SSb[off] = f2b(s);
    s = DC[bh * NC_ + c] * s + b2f(U[off]);
  }
}

// ---------------------------------------------------------------------------
// Phase C (MFMA): o_i = exp(cum_i)*q_i@Sstart + sum_{j<=i} exp(cum_i-cum_j)(q_i.k_j) v_j
// S^T step unswapped (Ps[i][j] u16x4 writes); term1/term2 swapped -> lane
// holds 4 consecutive v (row=q4) at fixed i (col=l15) -> u16x4 O stores.
// ---------------------------------------------------------------------------
__global__ void __launch_bounds__(256) gla_phaseC(const u16* __restrict__ Qb, const u16* __restrict__ Kb,
                                                  const u16* __restrict__ VT, const u16* __restrict__ SSb,
                                                  const float* __restrict__ LOGF, u16* __restrict__ Ob) {
  const int blk = blockIdx.x;
  const int bh = blk >> 5, c = blk & 31;
  const int b = bh >> 3, h = bh & 7;
  const int tid = threadIdx.x;
  const int wave = tid >> 6, lane = tid & 63;
  const int wr = wave >> 1, wc = wave & 1, l15 = lane & 15;
  const int q4i = (lane >> 4) * 4, q8 = (lane >> 4) * 8;
  __shared__ u16 SA[128 * 40];
  __shared__ u16 SB[128 * 40];
  __shared__ u16 Ps[128 * 136];
  __shared__ float cum[CHUNK_];
  __shared__ float cumE[CHUNK_];
  scan_chunk(LOGF + (size_t)bh * N_ + c * CHUNK_, cum, tid);
  if (tid < 128) cumE[tid] = __expf(cum[tid]);
  __syncthreads();
  const size_t rowbase = ((size_t)(b * N_ + c * CHUNK_)) * E_ + (size_t)h * R_;
  const u16* vtbase = VT + ((size_t)bh * R_) * N_ + (size_t)c * CHUNK_;
  const u16* ssbase = SSb + (size_t)blk * (R_ * R_);

  f32x4 acc[4][4];
#pragma unroll
  for (int i = 0; i < 4; i++)
#pragma unroll
    for (int j = 0; j < 4; j++) acc[i][j] = (f32x4){0.f, 0.f, 0.f, 0.f};

  // ---- S^T = K @ Q^T (row=j, col=i) ----
  for (int r0 = 0; r0 < R_; r0 += 32) {
    __syncthreads();
    stage32(SA, Kb + rowbase + r0, E_, tid);   // rows j
    stage32(SB, Qb + rowbase + r0, E_, tid);   // rows i
    __syncthreads();
    mfma16<false>(acc, SA, SB, wr, wc, l15, q8);
  }
  // ---- mask + decay -> Ps[i][j] ----
#pragma unroll
  for (int mi = 0; mi < 4; mi++) {
#pragma unroll
    for (int ni = 0; ni < 4; ni++) {
      int jb = wr * 64 + mi * 16 + q4i;
      int i = wc * 64 + ni * 16 + l15;
      float ci = cum[i];
      float4 cj = *(const float4*)&cum[jb];
      u16x4 pk;
      float cjv[4] = {cj.x, cj.y, cj.z, cj.w};
#pragma unroll
      for (int r = 0; r < 4; r++) {
        int j = jb + r;
        float w = (j <= i) ? __expf(ci - cjv[r]) : 0.f;
        pk[r] = f2b(acc[mi][ni][r] * w);
      }
      *(u16x4*)&Ps[i * 136 + jb] = pk;
    }
  }
  // ---- term1 (swapped): Q @ SS^T  (row=v, col=i) ----
#pragma unroll
  for (int i = 0; i < 4; i++)
#pragma unroll
    for (int j = 0; j < 4; j++) acc[i][j] = (f32x4){0.f, 0.f, 0.f, 0.f};
  for (int k0 = 0; k0 < R_; k0 += 32) {
    __syncthreads();
    stage32(SA, Qb + rowbase + k0, E_, tid);     // rows i
    stage32(SB, ssbase + k0, R_, tid);           // rows v (SS^T layout [v][k])
    __syncthreads();
    mfma16<true>(acc, SA, SB, wr, wc, l15, q8);
  }
  // scale by exp(cum_i): i = col = wr/mi/l15-mapped -> one scalar per (mi)
#pragma unroll
  for (int mi = 0; mi < 4; mi++) {
    float ei = cumE[wr * 64 + mi * 16 + l15];
#pragma unroll
    for (int ni = 0; ni < 4; ni++)
#pragma unroll
      for (int r = 0; r < 4; r++) acc[mi][ni][r] *= ei;
  }
  // ---- term2 (swapped): acc += P @ V^T (row=v, col=i) ----
  for (int j0 = 0; j0 < CHUNK_; j0 += 32) {
    __syncthreads();
    stage32(SB, vtbase + j0, N_, tid);           // rows v
    __syncthreads();
    if (wr == 1 || j0 < 64) {                    // wr==0 waves: i<64 -> j>=64 all masked
      bf16x8 af[4], bf[4];
#pragma unroll
      for (int mi = 0; mi < 4; mi++)
        af[mi] = *(const bf16x8*)&Ps[(wr * 64 + mi * 16 + l15) * 136 + j0 + q8];
#pragma unroll
      for (int ni = 0; ni < 4; ni++)
        bf[ni] = *(const bf16x8*)&SB[(wc * 64 + ni * 16 + l15) * 40 + q8];
#pragma unroll
      for (int mi = 0; mi < 4; mi++)
#pragma unroll
        for (int ni = 0; ni < 4; ni++)
          acc[mi][ni] = __builtin_amdgcn_mfma_f32_16x16x32_bf16(bf[ni], af[mi], acc[mi][ni], 0, 0, 0);
    }
  }
  // ---- write O (bf16, row-major [m][E]): u16x4 along v at fixed i ----
#pragma unroll
  for (int mi = 0; mi < 4; mi++) {
#pragma unroll
    for (int ni = 0; ni < 4; ni++) {
      int i = wr * 64 + mi * 16 + l15;
      int vb = wc * 64 + ni * 16 + q4i;
      u16x4 pk;
#pragma unroll
      for (int r = 0; r < 4; r++) pk[r] = f2b(acc[mi][ni][r]);
      *(u16x4*)&Ob[rowbase + (size_t)i * E_ + vb] = pk;
    }
  }
}

// ---------------------------------------------------------------------------
// o = o * gate (both bf16); LayerNorm(weight-only, fp32 gamma) -> bf16
// ---------------------------------------------------------------------------
__global__ void __launch_bounds__(256) gate_ln(const u16* __restrict__ O, const u16* __restrict__ G,
                                               const float* __restrict__ gamma, u16* __restrict__ OLN) {
  int row = blockIdx.x, tid = threadIdx.x;
  u16x4 o4 = *(const u16x4*)(O + (size_t)row * E_ + tid * 4);
  u16x4 g4 = *(const u16x4*)(G + (size_t)row * E_ + tid * 4);
  float x0 = b2f(o4[0]) * b2f(g4[0]), x1 = b2f(o4[1]) * b2f(g4[1]);
  float x2 = b2f(o4[2]) * b2f(g4[2]), x3 = b2f(o4[3]) * b2f(g4[3]);
  float s = x0 + x1 + x2 + x3;
  float sq = x0 * x0 + x1 * x1 + x2 * x2 + x3 * x3;
  __shared__ float red[8];
#pragma unroll
  for (int m = 1; m < 64; m <<= 1) { s += __shfl_xor(s, m); sq += __shfl_xor(sq, m); }
  int wid = tid >> 6;
  if ((tid & 63) == 0) { red[wid] = s; red[4 + wid] = sq; }
  __syncthreads();
  s = red[0] + red[1] + red[2] + red[3];
  sq = red[4] + red[5] + red[6] + red[7];
  float mu = s * (1.f / 1024.f);
  float var = sq * (1.f / 1024.f) - mu * mu;
  float rs = rsqrtf(var + 1e-5f);
  int e = tid * 4;
  u16x4 r4;
  r4[0] = f2b((x0 - mu) * rs * gamma[e + 0]);
  r4[1] = f2b((x1 - mu) * rs * gamma[e + 1]);
  r4[2] = f2b((x2 - mu) * rs * gamma[e + 2]);
  r4[3] = f2b((x3 - mu) * rs * gamma[e + 3]);
  *(u16x4*)(OLN + (size_t)row * E_ + e) = r4;
}

// ---------------------------------------------------------------------------
extern "C" void kernel_launch(void* const* d_in, const int* in_sizes, int n_in,
                              void* d_out, int out_size, void* d_ws, size_t ws_size,
                              hipStream_t stream) {
  (void)in_sizes; (void)n_in; (void)out_size; (void)ws_size;
  const float* x   = (const float*)d_in[0];
  const float* llb = (const float*)d_in[1];
  const float* Wq  = (const float*)d_in[2];
  const float* Wk  = (const float*)d_in[3];
  const float* Wv  = (const float*)d_in[4];
  const float* Wf  = (const float*)d_in[5];
  const float* Wb1 = (const float*)d_in[6];
  const float* Wb2 = (const float*)d_in[7];
  const float* Wg1 = (const float*)d_in[8];
  const float* Wg2 = (const float*)d_in[9];
  const float* gm  = (const float*)d_in[10];
  const float* Wo  = (const float*)d_in[11];
  float* out = (float*)d_out;

  char* ws = (char*)d_ws;
  const size_t SZB = (size_t)M_ * E_ * 2;            // 16.78 MB bf16 [M,E]
  u16*   Qb    = (u16*)(ws + 0 * SZB);               // q bf16 (OLN overlay later)
  u16*   Kb    = (u16*)(ws + 1 * SZB);
  u16*   KT    = (u16*)(ws + 2 * SZB);               // [B,H,R,N]
  u16*   VT    = (u16*)(ws + 3 * SZB);               // [B,H,R,N]
  u16*   BETAb = (u16*)(ws + 4 * SZB);               // beta -> O overlay
  u16*   GATEb = (u16*)(ws + 5 * SZB);
  u16*   SSb   = (u16*)(ws + 6 * SZB);               // chunk-start states bf16 [v][k]
  u16*   XB    = (u16*)(ws + 7 * SZB);
  u16*   U     = (u16*)(ws + 8 * SZB);               // bf16 [512][128][128]
  char*  tail  = ws + 8 * SZB + (size_t)BH_ * NC_ * R_ * R_ * 2;
  u16*   Wcat  = (u16*)tail;                         // [3456][1024]
  u16*   Wcat2 = Wcat + (size_t)3456 * 1024;         // [2048][256]
  u16*   WOb   = Wcat2 + (size_t)2048 * 256;         // [1024][1024]
  u16*   T1    = WOb + (size_t)E_ * E_;              // [M,256]
  float* LOGF  = (float*)(T1 + (size_t)M_ * 256);
  float* DC    = LOGF + (size_t)BH_ * N_;
  u16*   Ob    = BETAb;                              // overlay (beta dead after householder)
  u16*   OLN   = Qb;                                 // overlay (q dead after phaseC)

  CvtArgs ca;
  ca.src[0] = x;   ca.dst[0]  = XB;
  ca.src[1] = Wq;  ca.dst[1]  = Wcat;
  ca.src[2] = Wk;  ca.dst[2]  = Wcat + (size_t)1024 * 1024;
  ca.src[3] = Wv;  ca.dst[3]  = Wcat + (size_t)2048 * 1024;
  ca.src[4] = Wf;  ca.dst[4]  = Wcat + (size_t)3328 * 1024;
  ca.src[5] = Wb1; ca.dst[5]  = Wcat + (size_t)3072 * 1024;
  ca.src[6] = Wb2; ca.dst[6]  = Wcat2;
  ca.src[7] = Wg1; ca.dst[7]  = Wcat + (size_t)3200 * 1024;
  ca.src[8] = Wg2; ca.dst[8]  = Wcat2;
  ca.src[9] = Wo;  ca.dst[9]  = WOb;
  ca.dst[10] = Wcat + (size_t)3336 * 1024;           // zero pad rows

  dim3 blk(256);
  cvt_all<<<dim3(12928), blk, 0, stream>>>(ca);
  mega_gemm<<<dim3(27, 64), blk, 0, stream>>>(XB, Wcat, llb, Qb, Kb, KT, VT, T1, LOGF);
  bg_gemm<<<dim3(64, 16), blk, 0, stream>>>(T1, Wcat2, BETAb, GATEb);
  householder<<<dim3(M_), blk, 0, stream>>>(Qb, BETAb);
  gla_phaseA<<<dim3(BH_ * NC_), blk, 0, stream>>>(KT, VT, LOGF, U, DC);
  gla_phaseB<<<dim3(BH_ * 16384 / 256), blk, 0, stream>>>(U, DC, SSb);
  gla_phaseC<<<dim3(BH_ * NC_), blk, 0, stream>>>(Qb, Kb, VT, SSb, LOGF, Ob);
  gate_ln<<<dim3(M_), blk, 0, stream>>>(Ob, GATEb, gm, OLN);
  out_gemm<<<dim3(64, 8), blk, 0, stream>>>(OLN, WOb, out);
}